// Round 9
// baseline (144.561 us; speedup 1.0000x reference)
//
#include <hip/hip_runtime.h>
#include <cstdint>
#include <cstddef>

#define DI __device__ __forceinline__

typedef __attribute__((ext_vector_type(8))) short short8;
typedef __attribute__((ext_vector_type(4))) float f32x4;

DI float bf2f(unsigned short u) {
  union { unsigned int i; float f; } c; c.i = ((unsigned int)u) << 16; return c.f;
}
DI unsigned short f2bf(float f) {
  union { float fl; unsigned int i; } c; c.fl = f;
  return (unsigned short)((c.i + 0x7FFFu + ((c.i >> 16) & 1u)) >> 16);
}

// ---- workspace layout (bytes) ----
static const size_t OFF_MB   = 256;                       // u32[128] mask bitwords
static const size_t OFF_RBF  = 1024;                      // f32[136] rel_bias
static const size_t OFF_PBF  = 2048;                      // f32[512] proj_b
static const size_t OFF_AT   = 16384;                     // bf16 A_t[17][128][128]
static const size_t OFF_XQ   = OFF_AT + 557056;           // bf16 [2048][1024] (q|k)
static const size_t OFF_VT   = OFF_XQ + (size_t)4194304;  // bf16 [128bh][64d][128n]
static const size_t OFF_ATTO = OFF_VT + (size_t)2097152;  // bf16 [2048][512]

// ---- phase1: blocks 0..767 qkv GEMM (64x64 tile, 3 blocks/CU); 768..895 prep ----
__global__ __launch_bounds__(256) void k_phase1(
    const void* __restrict__ x, const void* __restrict__ qw,
    const void* __restrict__ kvw, const void* __restrict__ as,
    const unsigned char* __restrict__ mr, const void* __restrict__ rb,
    const void* __restrict__ pb, unsigned char* __restrict__ ws) {
  __shared__ unsigned short As[64 * 64];
  __shared__ unsigned short Bs[64 * 64];
  __shared__ int s_c0, s_3f, s_b1, s_odd;
  const int t = threadIdx.x;
  const int blk = blockIdx.x;

  if (t == 0) { s_c0 = 0; s_3f = 0; s_b1 = 0; s_odd = 0; }
  __syncthreads();
  // fmode self-detect (every block; 256B of x prefix, L2-broadcast after first)
  if (t < 128) {
    unsigned short u = ((const unsigned short*)x)[2 * t];
    int e = (u >> 7) & 0xFF;
    if (e >= 64 && e <= 150) atomicAdd(&s_c0, 1);
  }

  if (blk < 768) {
    // ============ qkv GEMM: C[2048,1536] = x @ [qw;kvw]^T, 64x64 tile ============
    __syncthreads();
    const int fmode = (s_c0 >= 96) ? 0 : 1;
    const int bm = (blk & 31) * 64, bn = (blk >> 5) * 64;
    const int wv = t >> 6, l = t & 63, ln = l & 15, qd = l >> 4;
    f32x4 acc[4] = {};
    const int g_row8 = l >> 3;
    const int g_ck = (l & 7) ^ g_row8;
    const int s_row = t >> 2;
    const int s_cb = (t & 3) * 2;
    for (int k0 = 0; k0 < 512; k0 += 64) {
      if (!fmode) {
        const unsigned short* xb = (const unsigned short*)x;
#pragma unroll
        for (int jj = 0; jj < 2; jj++) {
          int j = 2 * wv + jj;
          const unsigned short* g = xb + (size_t)(bm + j * 8 + g_row8) * 512 + k0 + g_ck * 8;
          __builtin_amdgcn_global_load_lds(
              (const __attribute__((address_space(1))) unsigned int*)g,
              (__attribute__((address_space(3))) unsigned int*)(&As[j * 512 + l * 8]),
              16, 0, 0);
        }
#pragma unroll
        for (int jj = 0; jj < 2; jj++) {
          int j = 2 * wv + jj;
          int row = bn + j * 8 + g_row8;
          const unsigned short* base = (row < 512)
              ? (const unsigned short*)qw + (size_t)row * 512
              : (const unsigned short*)kvw + (size_t)(row - 512) * 512;
          const unsigned short* g = base + k0 + g_ck * 8;
          __builtin_amdgcn_global_load_lds(
              (const __attribute__((address_space(1))) unsigned int*)g,
              (__attribute__((address_space(3))) unsigned int*)(&Bs[j * 512 + l * 8]),
              16, 0, 0);
        }
      } else {
        const float* ga = (const float*)x + (size_t)(bm + s_row) * 512 + k0 + s_cb * 8;
        int brow = bn + s_row;
        const float* gb = ((brow < 512) ? (const float*)qw + (size_t)brow * 512
                                        : (const float*)kvw + (size_t)(brow - 512) * 512)
                          + k0 + s_cb * 8;
#pragma unroll
        for (int cc = 0; cc < 2; cc++) {
          unsigned short ta[8], tb[8];
#pragma unroll
          for (int u = 0; u < 8; u++) { ta[u] = f2bf(ga[cc * 8 + u]); tb[u] = f2bf(gb[cc * 8 + u]); }
          int pc = (s_cb + cc) ^ (s_row & 7);
          *(uint4*)&As[s_row * 64 + pc * 8] = *(const uint4*)ta;
          *(uint4*)&Bs[s_row * 64 + pc * 8] = *(const uint4*)tb;
        }
      }
      __syncthreads();
#pragma unroll
      for (int kk = 0; kk < 64; kk += 32) {
        int c = (kk >> 3) + qd;
        short8 af = *(const short8*)&As[(wv * 16 + ln) * 64 + ((c ^ (ln & 7)) * 8)];
#pragma unroll
        for (int tj = 0; tj < 4; tj++) {
          short8 bf = *(const short8*)&Bs[(tj * 16 + ln) * 64 + ((c ^ (ln & 7)) * 8)];
          acc[tj] = __builtin_amdgcn_mfma_f32_16x16x32_bf16(af, bf, acc[tj], 0, 0, 0);
        }
      }
      __syncthreads();
    }
    unsigned short* XQ = (unsigned short*)(ws + OFF_XQ);
    unsigned short* VT = (unsigned short*)(ws + OFF_VT);
#pragma unroll
    for (int tj = 0; tj < 4; tj++) {
      int col = bn + tj * 16 + ln;
      if (col >= 1024) {                       // V -> transposed, packed 8B store
        int c1 = col - 1024;
        int row0 = bm + wv * 16 + qd * 4;
        int bh = (row0 >> 7) * 8 + (c1 >> 6);
        ushort4 pk;
        pk.x = f2bf(acc[tj][0]); pk.y = f2bf(acc[tj][1]);
        pk.z = f2bf(acc[tj][2]); pk.w = f2bf(acc[tj][3]);
        *(ushort4*)&VT[((size_t)bh * 64 + (c1 & 63)) * 128 + (row0 & 127)] = pk;
      } else {
#pragma unroll
        for (int i = 0; i < 4; i++) {
          int row = bm + wv * 16 + qd * 4 + i;
          XQ[(size_t)row * 1024 + col] = f2bf(acc[tj][i]);
        }
      }
    }
  } else {
    // ================= prep: A_t repack + mask bits + biases =================
    {
      int f3 = 0, b1 = 0, od = 0;
      for (int i = t; i < 2176; i += 256) {
        unsigned char bb = mr[i];
        if (bb == 0x3F) f3 = 1;
        if (bb) { if ((i & 3) == 1) b1 = 1; if (i & 3) od = 1; }
      }
      if (f3) atomicOr(&s_3f, 1);
      if (b1) atomicOr(&s_b1, 1);
      if (od) atomicOr(&s_odd, 1);
    }
    __syncthreads();
    const int fmode = (s_c0 >= 96) ? 0 : 1;
    const int mmode = s_3f ? (s_b1 ? 2 : 3) : (s_odd ? 0 : 1);
    const int gid = (blk - 768) * 256 + t;
    if (gid == 0) { ((int*)ws)[0] = fmode; ((int*)ws)[1] = mmode; }
    unsigned short* At = (unsigned short*)(ws + OFF_AT);
    unsigned int* MB = (unsigned int*)(ws + OFF_MB);
    float* RBf = (float*)(ws + OFF_RBF);
    float* PBf = (float*)(ws + OFF_PBF);
    const int gs = 128 * 256;
    for (int i = gid; i < 279304; i += gs) {
      if (i < 278528) {
        int r = i >> 14, mn = i & 16383;
        int si = mn * 17 + r;
        At[i] = fmode ? f2bf(((const float*)as)[si]) : ((const unsigned short*)as)[si];
      } else if (i < 278656) {
        int m = i - 278528;
        unsigned int bits = 0;
        for (int r = 0; r < 17; r++) {
          int j = m * 17 + r, v;
          if (mmode == 0)      v = mr[j] != 0;
          else if (mmode == 1) v = ((const int*)mr)[j] != 0;
          else if (mmode == 2) v = ((const unsigned short*)mr)[j] != 0;
          else                 v = ((const float*)mr)[j] != 0.0f;
          bits |= (unsigned int)v << r;
        }
        MB[m] = bits;
      } else if (i < 278792) {
        int j = i - 278656;
        RBf[j] = fmode ? ((const float*)rb)[j] : bf2f(((const unsigned short*)rb)[j]);
      } else {
        int j = i - 278792;
        PBf[j] = fmode ? ((const float*)pb)[j] : bf2f(((const unsigned short*)pb)[j]);
      }
    }
  }
}

// ---- 64x64-tile GEMM (proj), glld(16B) + XOR-swizzle, dual-dtype ----
struct GemmP {
  const void *A, *Bq, *Bkv;
  int bsplit;
  void* C; int ldc;
  const float* biasf;
  const int* flags;
  int aMask, bMask, oMask;
  int K;
};

__global__ __launch_bounds__(256) void k_gemm64(GemmP p) {
  __shared__ unsigned short As[64 * 64];
  __shared__ unsigned short Bs[64 * 64];
  const int fmode = p.flags[0];
  const int aF = fmode & p.aMask, bF = fmode & p.bMask, oF = fmode & p.oMask;
  const int bm = blockIdx.x * 64, bn = blockIdx.y * 64;
  const int t = threadIdx.x, wv = t >> 6, l = t & 63, ln = l & 15, qd = l >> 4;
  const int K = p.K;
  f32x4 acc[4] = {};
  const int g_row8 = l >> 3;
  const int g_ck = (l & 7) ^ g_row8;
  const int s_row = t >> 2;
  const int s_cb = (t & 3) * 2;
  for (int k0 = 0; k0 < K; k0 += 64) {
    if (!aF) {
#pragma unroll
      for (int jj = 0; jj < 2; jj++) {
        int j = 2 * wv + jj;
        const unsigned short* g = (const unsigned short*)p.A +
            (size_t)(bm + j * 8 + g_row8) * K + k0 + g_ck * 8;
        __builtin_amdgcn_global_load_lds(
            (const __attribute__((address_space(1))) unsigned int*)g,
            (__attribute__((address_space(3))) unsigned int*)(&As[j * 512 + l * 8]),
            16, 0, 0);
      }
    } else {
      const float* g = (const float*)p.A + (size_t)(bm + s_row) * K + k0 + s_cb * 8;
#pragma unroll
      for (int cc = 0; cc < 2; cc++) {
        unsigned short tmp[8];
#pragma unroll
        for (int u = 0; u < 8; u++) tmp[u] = f2bf(g[cc * 8 + u]);
        int pc = (s_cb + cc) ^ (s_row & 7);
        *(uint4*)&As[s_row * 64 + pc * 8] = *(const uint4*)tmp;
      }
    }
    if (!bF) {
#pragma unroll
      for (int jj = 0; jj < 2; jj++) {
        int j = 2 * wv + jj;
        int row = bn + j * 8 + g_row8;
        const unsigned short* base = (row < p.bsplit)
            ? (const unsigned short*)p.Bq + (size_t)row * K
            : (const unsigned short*)p.Bkv + (size_t)(row - p.bsplit) * K;
        const unsigned short* g = base + k0 + g_ck * 8;
        __builtin_amdgcn_global_load_lds(
            (const __attribute__((address_space(1))) unsigned int*)g,
            (__attribute__((address_space(3))) unsigned int*)(&Bs[j * 512 + l * 8]),
            16, 0, 0);
      }
    } else {
      int row = bn + s_row;
      const float* base = (row < p.bsplit)
          ? (const float*)p.Bq + (size_t)row * K
          : (const float*)p.Bkv + (size_t)(row - p.bsplit) * K;
      const float* g = base + k0 + s_cb * 8;
#pragma unroll
      for (int cc = 0; cc < 2; cc++) {
        unsigned short tmp[8];
#pragma unroll
        for (int u = 0; u < 8; u++) tmp[u] = f2bf(g[cc * 8 + u]);
        int pc = (s_cb + cc) ^ (s_row & 7);
        *(uint4*)&Bs[s_row * 64 + pc * 8] = *(const uint4*)tmp;
      }
    }
    __syncthreads();
#pragma unroll
    for (int kk = 0; kk < 64; kk += 32) {
      int c = (kk >> 3) + qd;
      short8 af = *(const short8*)&As[(wv * 16 + ln) * 64 + ((c ^ (ln & 7)) * 8)];
#pragma unroll
      for (int tj = 0; tj < 4; tj++) {
        short8 bf = *(const short8*)&Bs[(tj * 16 + ln) * 64 + ((c ^ (ln & 7)) * 8)];
        acc[tj] = __builtin_amdgcn_mfma_f32_16x16x32_bf16(af, bf, acc[tj], 0, 0, 0);
      }
    }
    __syncthreads();
  }
#pragma unroll
  for (int tj = 0; tj < 4; tj++) {
    int col = bn + tj * 16 + ln;
    float bv = p.biasf ? p.biasf[col] : 0.0f;
#pragma unroll
    for (int i = 0; i < 4; i++) {
      int row = bm + wv * 16 + qd * 4 + i;
      float v = acc[tj][i] + bv;
      if (oF) ((float*)p.C)[(size_t)row * p.ldc + col] = v;
      else    ((unsigned short*)p.C)[(size_t)row * p.ldc + col] = f2bf(v);
    }
  }
}

// ---- attention core: 512 blocks x 32 m-rows, 39.9KB LDS -> 3 blocks/CU ----
#define SST 132    // f32 per S row (pad); W bf16 overlays same rows (stride 264 u16)

__global__ __launch_bounds__(512, 6) void k_attn(
    const unsigned short* __restrict__ XQ, const unsigned short* __restrict__ VT,
    const unsigned short* __restrict__ AT, const unsigned int* __restrict__ MB,
    const float* __restrict__ RBf, unsigned short* __restrict__ ATTO) {
  __shared__ __align__(16) float Sf[32 * SST];          // 16896 B
  __shared__ __align__(16) unsigned short qs[32][72];   // 4608
  __shared__ __align__(16) unsigned short ks[128][72];  // 18432
  unsigned short* Wb = (unsigned short*)Sf;

  // 512 blocks = (slot 0..63) x (xcd 0..7); m-quarter pinned to an XCD pair
  const int i0 = blockIdx.x;
  const int xcd = i0 & 7, slot = i0 >> 3;
  const int mq = xcd >> 1;                 // 0..3 (32 m-rows each)
  const int bhid = slot * 2 + (xcd & 1);   // 0..127
  const int h = bhid & 7, b = bhid >> 3;
  const int bh = b * 8 + h;
  const int t = threadIdx.x;
  const int wv = t >> 6, l = t & 63, ln = l & 15, qd = l >> 4;

  // ---- staging: q(32x64), k(128x64); 1280 uint4 over 512 thr ----
  for (int it = t; it < 1280; it += 512) {
    int row = it >> 3, ck = it & 7;
    if (row < 32) {
      const unsigned short* g = XQ + (size_t)(b * 128 + mq * 32 + row) * 1024 + h * 64 + ck * 8;
      *(uint4*)&qs[row][ck * 8] = *(const uint4*)g;
    } else {
      int nr = row - 32;
      const unsigned short* g = XQ + (size_t)(b * 128 + nr) * 1024 + 512 + h * 64 + ck * 8;
      *(uint4*)&ks[nr][ck * 8] = *(const uint4*)g;
    }
  }
  __syncthreads();

  // ---- S(32x128) = q @ k^T * scale : 8 waves ----
  {
    f32x4 accS[2] = {};
    const int rt = wv & 1, ch = wv >> 1;
#pragma unroll
    for (int kk = 0; kk < 64; kk += 32) {
      short8 af = *(const short8*)&qs[rt * 16 + ln][kk + qd * 8];
#pragma unroll
      for (int tj = 0; tj < 2; tj++) {
        short8 bf = *(const short8*)&ks[ch * 32 + tj * 16 + ln][kk + qd * 8];
        accS[tj] = __builtin_amdgcn_mfma_f32_16x16x32_bf16(af, bf, accS[tj], 0, 0, 0);
      }
    }
#pragma unroll
    for (int tj = 0; tj < 2; tj++)
#pragma unroll
      for (int i = 0; i < 4; i++)
        Sf[(rt * 16 + qd * 4 + i) * SST + ch * 32 + tj * 16 + ln] =
            accS[tj][i] * 0.125f;
  }
  __syncthreads();

  // ---- fused single-pass logits+softmax+W : 16 thr/row x 8 n-values ----
  // max-free softmax: logits O(10) << 88 (fp32 exp limit); dividing by the sum
  // afterwards is mathematically identical to ref softmax.
  {
    const int ml = t >> 4, q16 = t & 15, n0 = q16 * 8;
    const int m = mq * 32 + ml;
    float sreg[8];
#pragma unroll
    for (int c4 = 0; c4 < 2; c4++) {
      float4 s4 = *(const float4*)&Sf[ml * SST + n0 + c4 * 4];
      sreg[c4 * 4 + 0] = s4.x; sreg[c4 * 4 + 1] = s4.y;
      sreg[c4 * 4 + 2] = s4.z; sreg[c4 * 4 + 3] = s4.w;
    }
    const unsigned short* abase = AT + (size_t)m * 128 + n0;
    const unsigned int mb = MB[m];
    float wacc[8];
#pragma unroll
    for (int j = 0; j < 8; j++) wacc[j] = 0.0f;
    float sum = 0.0f;
    uint4 ca = *(const uint4*)abase;
#pragma unroll
    for (int r = 0; r < 17; r++) {
      uint4 na;
      if (r + 1 < 17) na = *(const uint4*)(abase + (r + 1) * 16384);
      float av[8];
      const unsigned short* a8 = (const unsigned short*)&ca;
#pragma unroll
      for (int j = 0; j < 8; j++) av[j] = bf2f(a8[j]);
      float s = 0.0f;
#pragma unroll
      for (int j = 0; j < 8; j++) s += sreg[j] * av[j];
      s += __shfl_xor(s, 1);
      s += __shfl_xor(s, 2);
      s += __shfl_xor(s, 4);
      s += __shfl_xor(s, 8);
      float e = ((mb >> r) & 1) ? 0.0f : __expf(s + RBf[h * 17 + r]);
      sum += e;
#pragma unroll
      for (int j = 0; j < 8; j++) wacc[j] += e * av[j];
      ca = na;
    }
    const float inv = 1.0f / sum;
    unsigned short pk[8];
#pragma unroll
    for (int j = 0; j < 8; j++) pk[j] = f2bf(wacc[j] * inv);
    // W overlays same-row S bytes; the row's 16 threads are consecutive lanes
    // of one wave and all S reads precede these writes in program order
    *(uint4*)&Wb[ml * 264 + n0] = *(const uint4*)&pk[0];
  }
  __syncthreads();

  // ---- out(32x64) = W(32x128) @ v(128x64) : v^T fragments straight from L2 ----
  {
    f32x4 accO = {};
    const int rt = wv & 1, dt = wv >> 1;
    const int d = dt * 16 + ln;
    const unsigned short* vrow = VT + ((size_t)bh * 64 + d) * 128;
#pragma unroll
    for (int kk = 0; kk < 128; kk += 32) {
      short8 af = *(const short8*)&Wb[(rt * 16 + ln) * 264 + kk + qd * 8];
      short8 bf = *(const short8*)(vrow + kk + qd * 8);
      accO = __builtin_amdgcn_mfma_f32_16x16x32_bf16(af, bf, accO, 0, 0, 0);
    }
#pragma unroll
    for (int i = 0; i < 4; i++) {
      int row = b * 128 + mq * 32 + rt * 16 + qd * 4 + i;
      ATTO[(size_t)row * 512 + h * 64 + d] = f2bf(accO[i]);
    }
  }
}

extern "C" void kernel_launch(void* const* d_in, const int* in_sizes, int n_in,
                              void* d_out, int out_size, void* d_ws, size_t ws_size,
                              hipStream_t stream) {
  unsigned char* ws = (unsigned char*)d_ws;
  // 0:x 1:assignment 2:mask 3:q_w 4:kv_w 5:rel_bias 6:proj_w 7:proj_b
  k_phase1<<<896, 256, 0, stream>>>(d_in[0], d_in[3], d_in[4], d_in[1],
                                    (const unsigned char*)d_in[2],
                                    d_in[5], d_in[7], ws);
  k_attn<<<512, 512, 0, stream>>>((const unsigned short*)(ws + OFF_XQ),
                                  (const unsigned short*)(ws + OFF_VT),
                                  (const unsigned short*)(ws + OFF_AT),
                                  (const unsigned int*)(ws + OFF_MB),
                                  (const float*)(ws + OFF_RBF),
                                  (unsigned short*)(ws + OFF_ATTO));
  GemmP pp;
  pp.A = ws + OFF_ATTO; pp.Bq = d_in[6]; pp.Bkv = d_in[6]; pp.bsplit = 512;
  pp.C = d_out; pp.ldc = 512; pp.biasf = (const float*)(ws + OFF_PBF);
  pp.flags = (const int*)ws; pp.aMask = 0; pp.bMask = 1; pp.oMask = 1; pp.K = 512;
  k_gemm64<<<dim3(32, 8), 256, 0, stream>>>(pp);
}

// Round 10
// 117.955 us; speedup vs baseline: 1.2256x; 1.2256x over previous
//
#include <hip/hip_runtime.h>
#include <cstdint>
#include <cstddef>

#define DI __device__ __forceinline__

typedef __attribute__((ext_vector_type(8))) short short8;
typedef __attribute__((ext_vector_type(4))) float f32x4;

DI float bf2f(unsigned short u) {
  union { unsigned int i; float f; } c; c.i = ((unsigned int)u) << 16; return c.f;
}
DI unsigned short f2bf(float f) {
  union { float fl; unsigned int i; } c; c.fl = f;
  return (unsigned short)((c.i + 0x7FFFu + ((c.i >> 16) & 1u)) >> 16);
}

// ---- workspace layout (bytes) ----
static const size_t OFF_MB   = 256;                       // u32[128] mask bitwords
static const size_t OFF_RBF  = 1024;                      // f32[136] rel_bias
static const size_t OFF_PBF  = 2048;                      // f32[512] proj_b
static const size_t OFF_AT   = 16384;                     // bf16 A_t[17][128][128]
static const size_t OFF_XQ   = OFF_AT + 557056;           // bf16 [2048][1024] (q|k)
static const size_t OFF_VT   = OFF_XQ + (size_t)4194304;  // bf16 [128bh][64d][128n]
static const size_t OFF_ATTO = OFF_VT + (size_t)2097152;  // bf16 [2048][512]

// ---- phase1: blocks 0..767 qkv GEMM (64x64 tile, 3 blocks/CU); 768..895 prep ----
__global__ __launch_bounds__(256) void k_phase1(
    const void* __restrict__ x, const void* __restrict__ qw,
    const void* __restrict__ kvw, const void* __restrict__ as,
    const unsigned char* __restrict__ mr, const void* __restrict__ rb,
    const void* __restrict__ pb, unsigned char* __restrict__ ws) {
  __shared__ unsigned short As[64 * 64];
  __shared__ unsigned short Bs[64 * 64];
  __shared__ int s_c0, s_3f, s_b1, s_odd;
  const int t = threadIdx.x;
  const int blk = blockIdx.x;

  if (t == 0) { s_c0 = 0; s_3f = 0; s_b1 = 0; s_odd = 0; }
  __syncthreads();
  // fmode self-detect (every block; 256B of x prefix, L2-broadcast after first)
  if (t < 128) {
    unsigned short u = ((const unsigned short*)x)[2 * t];
    int e = (u >> 7) & 0xFF;
    if (e >= 64 && e <= 150) atomicAdd(&s_c0, 1);
  }

  if (blk < 768) {
    // ============ qkv GEMM: C[2048,1536] = x @ [qw;kvw]^T, 64x64 tile ============
    __syncthreads();
    const int fmode = (s_c0 >= 96) ? 0 : 1;
    const int bm = (blk & 31) * 64, bn = (blk >> 5) * 64;
    const int wv = t >> 6, l = t & 63, ln = l & 15, qd = l >> 4;
    f32x4 acc[4] = {};
    const int g_row8 = l >> 3;
    const int g_ck = (l & 7) ^ g_row8;
    const int s_row = t >> 2;
    const int s_cb = (t & 3) * 2;
    for (int k0 = 0; k0 < 512; k0 += 64) {
      if (!fmode) {
        const unsigned short* xb = (const unsigned short*)x;
#pragma unroll
        for (int jj = 0; jj < 2; jj++) {
          int j = 2 * wv + jj;
          const unsigned short* g = xb + (size_t)(bm + j * 8 + g_row8) * 512 + k0 + g_ck * 8;
          __builtin_amdgcn_global_load_lds(
              (const __attribute__((address_space(1))) unsigned int*)g,
              (__attribute__((address_space(3))) unsigned int*)(&As[j * 512 + l * 8]),
              16, 0, 0);
        }
#pragma unroll
        for (int jj = 0; jj < 2; jj++) {
          int j = 2 * wv + jj;
          int row = bn + j * 8 + g_row8;
          const unsigned short* base = (row < 512)
              ? (const unsigned short*)qw + (size_t)row * 512
              : (const unsigned short*)kvw + (size_t)(row - 512) * 512;
          const unsigned short* g = base + k0 + g_ck * 8;
          __builtin_amdgcn_global_load_lds(
              (const __attribute__((address_space(1))) unsigned int*)g,
              (__attribute__((address_space(3))) unsigned int*)(&Bs[j * 512 + l * 8]),
              16, 0, 0);
        }
      } else {
        const float* ga = (const float*)x + (size_t)(bm + s_row) * 512 + k0 + s_cb * 8;
        int brow = bn + s_row;
        const float* gb = ((brow < 512) ? (const float*)qw + (size_t)brow * 512
                                        : (const float*)kvw + (size_t)(brow - 512) * 512)
                          + k0 + s_cb * 8;
#pragma unroll
        for (int cc = 0; cc < 2; cc++) {
          unsigned short ta[8], tb[8];
#pragma unroll
          for (int u = 0; u < 8; u++) { ta[u] = f2bf(ga[cc * 8 + u]); tb[u] = f2bf(gb[cc * 8 + u]); }
          int pc = (s_cb + cc) ^ (s_row & 7);
          *(uint4*)&As[s_row * 64 + pc * 8] = *(const uint4*)ta;
          *(uint4*)&Bs[s_row * 64 + pc * 8] = *(const uint4*)tb;
        }
      }
      __syncthreads();
#pragma unroll
      for (int kk = 0; kk < 64; kk += 32) {
        int c = (kk >> 3) + qd;
        short8 af = *(const short8*)&As[(wv * 16 + ln) * 64 + ((c ^ (ln & 7)) * 8)];
#pragma unroll
        for (int tj = 0; tj < 4; tj++) {
          short8 bf = *(const short8*)&Bs[(tj * 16 + ln) * 64 + ((c ^ (ln & 7)) * 8)];
          acc[tj] = __builtin_amdgcn_mfma_f32_16x16x32_bf16(af, bf, acc[tj], 0, 0, 0);
        }
      }
      __syncthreads();
    }
    unsigned short* XQ = (unsigned short*)(ws + OFF_XQ);
    unsigned short* VT = (unsigned short*)(ws + OFF_VT);
#pragma unroll
    for (int tj = 0; tj < 4; tj++) {
      int col = bn + tj * 16 + ln;
      if (col >= 1024) {                       // V -> transposed, packed 8B store
        int c1 = col - 1024;
        int row0 = bm + wv * 16 + qd * 4;
        int bh = (row0 >> 7) * 8 + (c1 >> 6);
        ushort4 pk;
        pk.x = f2bf(acc[tj][0]); pk.y = f2bf(acc[tj][1]);
        pk.z = f2bf(acc[tj][2]); pk.w = f2bf(acc[tj][3]);
        *(ushort4*)&VT[((size_t)bh * 64 + (c1 & 63)) * 128 + (row0 & 127)] = pk;
      } else {
#pragma unroll
        for (int i = 0; i < 4; i++) {
          int row = bm + wv * 16 + qd * 4 + i;
          XQ[(size_t)row * 1024 + col] = f2bf(acc[tj][i]);
        }
      }
    }
  } else {
    // ================= prep: A_t repack + mask bits + biases =================
    {
      int f3 = 0, b1 = 0, od = 0;
      for (int i = t; i < 2176; i += 256) {
        unsigned char bb = mr[i];
        if (bb == 0x3F) f3 = 1;
        if (bb) { if ((i & 3) == 1) b1 = 1; if (i & 3) od = 1; }
      }
      if (f3) atomicOr(&s_3f, 1);
      if (b1) atomicOr(&s_b1, 1);
      if (od) atomicOr(&s_odd, 1);
    }
    __syncthreads();
    const int fmode = (s_c0 >= 96) ? 0 : 1;
    const int mmode = s_3f ? (s_b1 ? 2 : 3) : (s_odd ? 0 : 1);
    const int gid = (blk - 768) * 256 + t;
    if (gid == 0) { ((int*)ws)[0] = fmode; ((int*)ws)[1] = mmode; }
    unsigned short* At = (unsigned short*)(ws + OFF_AT);
    unsigned int* MB = (unsigned int*)(ws + OFF_MB);
    float* RBf = (float*)(ws + OFF_RBF);
    float* PBf = (float*)(ws + OFF_PBF);
    const int gs = 128 * 256;
    for (int i = gid; i < 279304; i += gs) {
      if (i < 278528) {
        int r = i >> 14, mn = i & 16383;
        int si = mn * 17 + r;
        At[i] = fmode ? f2bf(((const float*)as)[si]) : ((const unsigned short*)as)[si];
      } else if (i < 278656) {
        int m = i - 278528;
        unsigned int bits = 0;
        for (int r = 0; r < 17; r++) {
          int j = m * 17 + r, v;
          if (mmode == 0)      v = mr[j] != 0;
          else if (mmode == 1) v = ((const int*)mr)[j] != 0;
          else if (mmode == 2) v = ((const unsigned short*)mr)[j] != 0;
          else                 v = ((const float*)mr)[j] != 0.0f;
          bits |= (unsigned int)v << r;
        }
        MB[m] = bits;
      } else if (i < 278792) {
        int j = i - 278656;
        RBf[j] = fmode ? ((const float*)rb)[j] : bf2f(((const unsigned short*)rb)[j]);
      } else {
        int j = i - 278792;
        PBf[j] = fmode ? ((const float*)pb)[j] : bf2f(((const unsigned short*)pb)[j]);
      }
    }
  }
}

// ---- 64x64-tile GEMM (proj), glld(16B) + XOR-swizzle, dual-dtype ----
struct GemmP {
  const void *A, *Bq, *Bkv;
  int bsplit;
  void* C; int ldc;
  const float* biasf;
  const int* flags;
  int aMask, bMask, oMask;
  int K;
};

__global__ __launch_bounds__(256) void k_gemm64(GemmP p) {
  __shared__ unsigned short As[64 * 64];
  __shared__ unsigned short Bs[64 * 64];
  const int fmode = p.flags[0];
  const int aF = fmode & p.aMask, bF = fmode & p.bMask, oF = fmode & p.oMask;
  const int bm = blockIdx.x * 64, bn = blockIdx.y * 64;
  const int t = threadIdx.x, wv = t >> 6, l = t & 63, ln = l & 15, qd = l >> 4;
  const int K = p.K;
  f32x4 acc[4] = {};
  const int g_row8 = l >> 3;
  const int g_ck = (l & 7) ^ g_row8;
  const int s_row = t >> 2;
  const int s_cb = (t & 3) * 2;
  for (int k0 = 0; k0 < K; k0 += 64) {
    if (!aF) {
#pragma unroll
      for (int jj = 0; jj < 2; jj++) {
        int j = 2 * wv + jj;
        const unsigned short* g = (const unsigned short*)p.A +
            (size_t)(bm + j * 8 + g_row8) * K + k0 + g_ck * 8;
        __builtin_amdgcn_global_load_lds(
            (const __attribute__((address_space(1))) unsigned int*)g,
            (__attribute__((address_space(3))) unsigned int*)(&As[j * 512 + l * 8]),
            16, 0, 0);
      }
    } else {
      const float* g = (const float*)p.A + (size_t)(bm + s_row) * K + k0 + s_cb * 8;
#pragma unroll
      for (int cc = 0; cc < 2; cc++) {
        unsigned short tmp[8];
#pragma unroll
        for (int u = 0; u < 8; u++) tmp[u] = f2bf(g[cc * 8 + u]);
        int pc = (s_cb + cc) ^ (s_row & 7);
        *(uint4*)&As[s_row * 64 + pc * 8] = *(const uint4*)tmp;
      }
    }
    if (!bF) {
#pragma unroll
      for (int jj = 0; jj < 2; jj++) {
        int j = 2 * wv + jj;
        int row = bn + j * 8 + g_row8;
        const unsigned short* base = (row < p.bsplit)
            ? (const unsigned short*)p.Bq + (size_t)row * K
            : (const unsigned short*)p.Bkv + (size_t)(row - p.bsplit) * K;
        const unsigned short* g = base + k0 + g_ck * 8;
        __builtin_amdgcn_global_load_lds(
            (const __attribute__((address_space(1))) unsigned int*)g,
            (__attribute__((address_space(3))) unsigned int*)(&Bs[j * 512 + l * 8]),
            16, 0, 0);
      }
    } else {
      int row = bn + s_row;
      const float* base = (row < p.bsplit)
          ? (const float*)p.Bq + (size_t)row * K
          : (const float*)p.Bkv + (size_t)(row - p.bsplit) * K;
      const float* g = base + k0 + s_cb * 8;
#pragma unroll
      for (int cc = 0; cc < 2; cc++) {
        unsigned short tmp[8];
#pragma unroll
        for (int u = 0; u < 8; u++) tmp[u] = f2bf(g[cc * 8 + u]);
        int pc = (s_cb + cc) ^ (s_row & 7);
        *(uint4*)&Bs[s_row * 64 + pc * 8] = *(const uint4*)tmp;
      }
    }
    __syncthreads();
#pragma unroll
    for (int kk = 0; kk < 64; kk += 32) {
      int c = (kk >> 3) + qd;
      short8 af = *(const short8*)&As[(wv * 16 + ln) * 64 + ((c ^ (ln & 7)) * 8)];
#pragma unroll
      for (int tj = 0; tj < 4; tj++) {
        short8 bf = *(const short8*)&Bs[(tj * 16 + ln) * 64 + ((c ^ (ln & 7)) * 8)];
        acc[tj] = __builtin_amdgcn_mfma_f32_16x16x32_bf16(af, bf, acc[tj], 0, 0, 0);
      }
    }
    __syncthreads();
  }
#pragma unroll
  for (int tj = 0; tj < 4; tj++) {
    int col = bn + tj * 16 + ln;
    float bv = p.biasf ? p.biasf[col] : 0.0f;
#pragma unroll
    for (int i = 0; i < 4; i++) {
      int row = bm + wv * 16 + qd * 4 + i;
      float v = acc[tj][i] + bv;
      if (oF) ((float*)p.C)[(size_t)row * p.ldc + col] = v;
      else    ((unsigned short*)p.C)[(size_t)row * p.ldc + col] = f2bf(v);
    }
  }
}

// ---- attention core (r8-proven): 512 blocks x 32 m-rows, 57.3KB LDS = 2 blocks/CU ----
#define SST 132    // f32 per S row (pad); W bf16 overlays same rows (stride 264 u16)

__global__ __launch_bounds__(512) void k_attn(
    const unsigned short* __restrict__ XQ, const unsigned short* __restrict__ VT,
    const unsigned short* __restrict__ AT, const unsigned int* __restrict__ MB,
    const float* __restrict__ RBf, unsigned short* __restrict__ ATTO) {
  __shared__ __align__(16) float Sf[32 * SST];          // 16896 B
  __shared__ __align__(16) unsigned short qs[32][72];   // 4608
  __shared__ __align__(16) unsigned short ks[128][72];  // 18432
  __shared__ __align__(16) unsigned short vs[64][136];  // 17408
  unsigned short* Wb = (unsigned short*)Sf;

  // 512 blocks = (slot 0..63) x (xcd 0..7); m-quarter pinned to an XCD pair
  // -> per-L2 A_t hot set = 139 KB.
  const int i0 = blockIdx.x;
  const int xcd = i0 & 7, slot = i0 >> 3;
  const int mq = xcd >> 1;                 // 0..3 (32 m-rows each)
  const int bhid = slot * 2 + (xcd & 1);   // 0..127
  const int h = bhid & 7, b = bhid >> 3;
  const int bh = b * 8 + h;
  const int t = threadIdx.x;
  const int wv = t >> 6, l = t & 63, ln = l & 15, qd = l >> 4;

  // ---- staging: q(32x64), k(128x64), vT(64x128) ----
  for (int it = t; it < 1280; it += 512) {
    int row = it >> 3, ck = it & 7;
    if (row < 32) {
      const unsigned short* g = XQ + (size_t)(b * 128 + mq * 32 + row) * 1024 + h * 64 + ck * 8;
      *(uint4*)&qs[row][ck * 8] = *(const uint4*)g;
    } else {
      int nr = row - 32;
      const unsigned short* g = XQ + (size_t)(b * 128 + nr) * 1024 + 512 + h * 64 + ck * 8;
      *(uint4*)&ks[nr][ck * 8] = *(const uint4*)g;
    }
  }
  for (int it = t; it < 1024; it += 512) {
    int d = it >> 4, ck = it & 15;
    *(uint4*)&vs[d][ck * 8] = *(const uint4*)(VT + ((size_t)bh * 64 + d) * 128 + ck * 8);
  }
  __syncthreads();

  // ---- S(32x128) = q @ k^T * scale : 8 waves ----
  {
    f32x4 accS[2] = {};
    const int rt = wv & 1, ch = wv >> 1;
#pragma unroll
    for (int kk = 0; kk < 64; kk += 32) {
      short8 af = *(const short8*)&qs[rt * 16 + ln][kk + qd * 8];
#pragma unroll
      for (int tj = 0; tj < 2; tj++) {
        short8 bf = *(const short8*)&ks[ch * 32 + tj * 16 + ln][kk + qd * 8];
        accS[tj] = __builtin_amdgcn_mfma_f32_16x16x32_bf16(af, bf, accS[tj], 0, 0, 0);
      }
    }
#pragma unroll
    for (int tj = 0; tj < 2; tj++)
#pragma unroll
      for (int i = 0; i < 4; i++)
        Sf[(rt * 16 + qd * 4 + i) * SST + ch * 32 + tj * 16 + ln] =
            accS[tj][i] * 0.125f;
  }
  __syncthreads();

  // ---- fused single-pass logits+softmax+W : 16 thr/row x 8 n-values ----
  // max-free softmax: logits O(10) << 88 (fp32 exp limit); dividing by the sum
  // afterwards is mathematically identical to ref softmax.
  {
    const int ml = t >> 4, q16 = t & 15, n0 = q16 * 8;
    const int m = mq * 32 + ml;
    float sreg[8];
#pragma unroll
    for (int c4 = 0; c4 < 2; c4++) {
      float4 s4 = *(const float4*)&Sf[ml * SST + n0 + c4 * 4];
      sreg[c4 * 4 + 0] = s4.x; sreg[c4 * 4 + 1] = s4.y;
      sreg[c4 * 4 + 2] = s4.z; sreg[c4 * 4 + 3] = s4.w;
    }
    const unsigned short* abase = AT + (size_t)m * 128 + n0;
    const unsigned int mb = MB[m];
    float wacc[8];
#pragma unroll
    for (int j = 0; j < 8; j++) wacc[j] = 0.0f;
    float sum = 0.0f;
    uint4 ca = *(const uint4*)abase;
#pragma unroll
    for (int r = 0; r < 17; r++) {
      uint4 na;
      if (r + 1 < 17) na = *(const uint4*)(abase + (r + 1) * 16384);
      float av[8];
      const unsigned short* a8 = (const unsigned short*)&ca;
#pragma unroll
      for (int j = 0; j < 8; j++) av[j] = bf2f(a8[j]);
      float s = 0.0f;
#pragma unroll
      for (int j = 0; j < 8; j++) s += sreg[j] * av[j];
      s += __shfl_xor(s, 1);
      s += __shfl_xor(s, 2);
      s += __shfl_xor(s, 4);
      s += __shfl_xor(s, 8);
      float e = ((mb >> r) & 1) ? 0.0f : __expf(s + RBf[h * 17 + r]);
      sum += e;
#pragma unroll
      for (int j = 0; j < 8; j++) wacc[j] += e * av[j];
      ca = na;
    }
    const float inv = 1.0f / sum;
    unsigned short pk[8];
#pragma unroll
    for (int j = 0; j < 8; j++) pk[j] = f2bf(wacc[j] * inv);
    // W overlays same-row S bytes; the row's 16 threads are consecutive lanes
    // of one wave and all S reads precede these writes in program order
    *(uint4*)&Wb[ml * 264 + n0] = *(const uint4*)&pk[0];
  }
  __syncthreads();

  // ---- out(32x64) = W(32x128) @ v(128x64) : 8 waves, 1 tile each ----
  {
    f32x4 accO = {};
    const int rt = wv & 1, dt = wv >> 1;
    const int d = dt * 16 + ln;
#pragma unroll
    for (int kk = 0; kk < 128; kk += 32) {
      short8 af = *(const short8*)&Wb[(rt * 16 + ln) * 264 + kk + qd * 8];
      short8 bf = *(const short8*)&vs[d][kk + qd * 8];
      accO = __builtin_amdgcn_mfma_f32_16x16x32_bf16(af, bf, accO, 0, 0, 0);
    }
#pragma unroll
    for (int i = 0; i < 4; i++) {
      int row = b * 128 + mq * 32 + rt * 16 + qd * 4 + i;
      ATTO[(size_t)row * 512 + h * 64 + d] = f2bf(accO[i]);
    }
  }
}

extern "C" void kernel_launch(void* const* d_in, const int* in_sizes, int n_in,
                              void* d_out, int out_size, void* d_ws, size_t ws_size,
                              hipStream_t stream) {
  unsigned char* ws = (unsigned char*)d_ws;
  // 0:x 1:assignment 2:mask 3:q_w 4:kv_w 5:rel_bias 6:proj_w 7:proj_b
  k_phase1<<<896, 256, 0, stream>>>(d_in[0], d_in[3], d_in[4], d_in[1],
                                    (const unsigned char*)d_in[2],
                                    d_in[5], d_in[7], ws);
  k_attn<<<512, 512, 0, stream>>>((const unsigned short*)(ws + OFF_XQ),
                                  (const unsigned short*)(ws + OFF_VT),
                                  (const unsigned short*)(ws + OFF_AT),
                                  (const unsigned int*)(ws + OFF_MB),
                                  (const float*)(ws + OFF_RBF),
                                  (unsigned short*)(ws + OFF_ATTO));
  GemmP pp;
  pp.A = ws + OFF_ATTO; pp.Bq = d_in[6]; pp.Bkv = d_in[6]; pp.bsplit = 512;
  pp.C = d_out; pp.ldc = 512; pp.biasf = (const float*)(ws + OFF_PBF);
  pp.flags = (const int*)ws; pp.aMask = 0; pp.bMask = 1; pp.oMask = 1; pp.K = 512;
  k_gemm64<<<dim3(32, 8), 256, 0, stream>>>(pp);
}

// Round 11
// 114.606 us; speedup vs baseline: 1.2614x; 1.0292x over previous
//
#include <hip/hip_runtime.h>
#include <cstdint>
#include <cstddef>

#define DI __device__ __forceinline__

typedef __attribute__((ext_vector_type(8))) short short8;
typedef __attribute__((ext_vector_type(4))) float f32x4;

DI float bf2f(unsigned short u) {
  union { unsigned int i; float f; } c; c.i = ((unsigned int)u) << 16; return c.f;
}
DI unsigned short f2bf(float f) {
  union { float fl; unsigned int i; } c; c.fl = f;
  return (unsigned short)((c.i + 0x7FFFu + ((c.i >> 16) & 1u)) >> 16);
}

// ---- workspace layout (bytes) ----
static const size_t OFF_MB   = 256;                       // u32[128] mask bitwords
static const size_t OFF_RBF  = 1024;                      // f32[136] rel_bias
static const size_t OFF_PBF  = 2048;                      // f32[512] proj_b
static const size_t OFF_AT   = 16384;                     // bf16 A_t[17][128][128]
static const size_t OFF_XQ   = OFF_AT + 557056;           // bf16 [2048][1024] (q|k)
static const size_t OFF_VT   = OFF_XQ + (size_t)4194304;  // bf16 [128bh][64d][128n]
static const size_t OFF_ATTO = OFF_VT + (size_t)2097152;  // bf16 [2048][512]

// ---- phase1: blocks 0..767 qkv GEMM (64x64 tile, 3 blocks/CU); 768..895 prep ----
__global__ __launch_bounds__(256) void k_phase1(
    const void* __restrict__ x, const void* __restrict__ qw,
    const void* __restrict__ kvw, const void* __restrict__ as,
    const unsigned char* __restrict__ mr, const void* __restrict__ rb,
    const void* __restrict__ pb, unsigned char* __restrict__ ws) {
  __shared__ unsigned short As[64 * 64];
  __shared__ unsigned short Bs[64 * 64];
  __shared__ int s_c0, s_3f, s_b1, s_odd;
  const int t = threadIdx.x;
  const int blk = blockIdx.x;

  if (t == 0) { s_c0 = 0; s_3f = 0; s_b1 = 0; s_odd = 0; }
  __syncthreads();
  // fmode self-detect (every block; 256B of x prefix, L2-broadcast after first)
  if (t < 128) {
    unsigned short u = ((const unsigned short*)x)[2 * t];
    int e = (u >> 7) & 0xFF;
    if (e >= 64 && e <= 150) atomicAdd(&s_c0, 1);
  }

  if (blk < 768) {
    // ============ qkv GEMM: C[2048,1536] = x @ [qw;kvw]^T, 64x64 tile ============
    __syncthreads();
    const int fmode = (s_c0 >= 96) ? 0 : 1;
    const int bm = (blk & 31) * 64, bn = (blk >> 5) * 64;
    const int wv = t >> 6, l = t & 63, ln = l & 15, qd = l >> 4;
    f32x4 acc[4] = {};
    const int g_row8 = l >> 3;
    const int g_ck = (l & 7) ^ g_row8;
    const int s_row = t >> 2;
    const int s_cb = (t & 3) * 2;
    for (int k0 = 0; k0 < 512; k0 += 64) {
      if (!fmode) {
        const unsigned short* xb = (const unsigned short*)x;
#pragma unroll
        for (int jj = 0; jj < 2; jj++) {
          int j = 2 * wv + jj;
          const unsigned short* g = xb + (size_t)(bm + j * 8 + g_row8) * 512 + k0 + g_ck * 8;
          __builtin_amdgcn_global_load_lds(
              (const __attribute__((address_space(1))) unsigned int*)g,
              (__attribute__((address_space(3))) unsigned int*)(&As[j * 512 + l * 8]),
              16, 0, 0);
        }
#pragma unroll
        for (int jj = 0; jj < 2; jj++) {
          int j = 2 * wv + jj;
          int row = bn + j * 8 + g_row8;
          const unsigned short* base = (row < 512)
              ? (const unsigned short*)qw + (size_t)row * 512
              : (const unsigned short*)kvw + (size_t)(row - 512) * 512;
          const unsigned short* g = base + k0 + g_ck * 8;
          __builtin_amdgcn_global_load_lds(
              (const __attribute__((address_space(1))) unsigned int*)g,
              (__attribute__((address_space(3))) unsigned int*)(&Bs[j * 512 + l * 8]),
              16, 0, 0);
        }
      } else {
        const float* ga = (const float*)x + (size_t)(bm + s_row) * 512 + k0 + s_cb * 8;
        int brow = bn + s_row;
        const float* gb = ((brow < 512) ? (const float*)qw + (size_t)brow * 512
                                        : (const float*)kvw + (size_t)(brow - 512) * 512)
                          + k0 + s_cb * 8;
#pragma unroll
        for (int cc = 0; cc < 2; cc++) {
          unsigned short ta[8], tb[8];
#pragma unroll
          for (int u = 0; u < 8; u++) { ta[u] = f2bf(ga[cc * 8 + u]); tb[u] = f2bf(gb[cc * 8 + u]); }
          int pc = (s_cb + cc) ^ (s_row & 7);
          *(uint4*)&As[s_row * 64 + pc * 8] = *(const uint4*)ta;
          *(uint4*)&Bs[s_row * 64 + pc * 8] = *(const uint4*)tb;
        }
      }
      __syncthreads();
#pragma unroll
      for (int kk = 0; kk < 64; kk += 32) {
        int c = (kk >> 3) + qd;
        short8 af = *(const short8*)&As[(wv * 16 + ln) * 64 + ((c ^ (ln & 7)) * 8)];
#pragma unroll
        for (int tj = 0; tj < 4; tj++) {
          short8 bf = *(const short8*)&Bs[(tj * 16 + ln) * 64 + ((c ^ (ln & 7)) * 8)];
          acc[tj] = __builtin_amdgcn_mfma_f32_16x16x32_bf16(af, bf, acc[tj], 0, 0, 0);
        }
      }
      __syncthreads();
    }
    unsigned short* XQ = (unsigned short*)(ws + OFF_XQ);
    unsigned short* VT = (unsigned short*)(ws + OFF_VT);
#pragma unroll
    for (int tj = 0; tj < 4; tj++) {
      int col = bn + tj * 16 + ln;
      if (col >= 1024) {                       // V -> transposed, packed 8B store
        int c1 = col - 1024;
        int row0 = bm + wv * 16 + qd * 4;
        int bh = (row0 >> 7) * 8 + (c1 >> 6);
        ushort4 pk;
        pk.x = f2bf(acc[tj][0]); pk.y = f2bf(acc[tj][1]);
        pk.z = f2bf(acc[tj][2]); pk.w = f2bf(acc[tj][3]);
        *(ushort4*)&VT[((size_t)bh * 64 + (c1 & 63)) * 128 + (row0 & 127)] = pk;
      } else {
#pragma unroll
        for (int i = 0; i < 4; i++) {
          int row = bm + wv * 16 + qd * 4 + i;
          XQ[(size_t)row * 1024 + col] = f2bf(acc[tj][i]);
        }
      }
    }
  } else {
    // ================= prep: A_t repack + mask bits + biases =================
    {
      int f3 = 0, b1 = 0, od = 0;
      for (int i = t; i < 2176; i += 256) {
        unsigned char bb = mr[i];
        if (bb == 0x3F) f3 = 1;
        if (bb) { if ((i & 3) == 1) b1 = 1; if (i & 3) od = 1; }
      }
      if (f3) atomicOr(&s_3f, 1);
      if (b1) atomicOr(&s_b1, 1);
      if (od) atomicOr(&s_odd, 1);
    }
    __syncthreads();
    const int fmode = (s_c0 >= 96) ? 0 : 1;
    const int mmode = s_3f ? (s_b1 ? 2 : 3) : (s_odd ? 0 : 1);
    const int gid = (blk - 768) * 256 + t;
    if (gid == 0) { ((int*)ws)[0] = fmode; ((int*)ws)[1] = mmode; }
    unsigned short* At = (unsigned short*)(ws + OFF_AT);
    unsigned int* MB = (unsigned int*)(ws + OFF_MB);
    float* RBf = (float*)(ws + OFF_RBF);
    float* PBf = (float*)(ws + OFF_PBF);
    const int gs = 128 * 256;
    for (int i = gid; i < 279304; i += gs) {
      if (i < 278528) {
        int r = i >> 14, mn = i & 16383;
        int si = mn * 17 + r;
        At[i] = fmode ? f2bf(((const float*)as)[si]) : ((const unsigned short*)as)[si];
      } else if (i < 278656) {
        int m = i - 278528;
        unsigned int bits = 0;
        for (int r = 0; r < 17; r++) {
          int j = m * 17 + r, v;
          if (mmode == 0)      v = mr[j] != 0;
          else if (mmode == 1) v = ((const int*)mr)[j] != 0;
          else if (mmode == 2) v = ((const unsigned short*)mr)[j] != 0;
          else                 v = ((const float*)mr)[j] != 0.0f;
          bits |= (unsigned int)v << r;
        }
        MB[m] = bits;
      } else if (i < 278792) {
        int j = i - 278656;
        RBf[j] = fmode ? ((const float*)rb)[j] : bf2f(((const unsigned short*)rb)[j]);
      } else {
        int j = i - 278792;
        PBf[j] = fmode ? ((const float*)pb)[j] : bf2f(((const unsigned short*)pb)[j]);
      }
    }
  }
}

// ---- proj GEMM: 64x32 tiles, 512 blocks (~2-3/CU) ----
__global__ __launch_bounds__(256) void k_proj(
    const unsigned short* __restrict__ A,   // ATTO bf16 [2048][512]
    const void* __restrict__ Bw,            // proj_w raw
    const float* __restrict__ biasf,
    const int* __restrict__ flags, void* __restrict__ C) {
  __shared__ unsigned short As[64 * 64];
  __shared__ unsigned short Bs[32 * 64];
  const int fmode = flags[0];
  const int bm = blockIdx.x * 64, bn = blockIdx.y * 32;
  const int t = threadIdx.x, wv = t >> 6, l = t & 63, ln = l & 15, qd = l >> 4;
  f32x4 acc[2] = {};
  const int g_row8 = l >> 3;
  const int g_ck = (l & 7) ^ g_row8;
  for (int k0 = 0; k0 < 512; k0 += 64) {
    // A: always bf16 (internal), 2 glld per wave
#pragma unroll
    for (int jj = 0; jj < 2; jj++) {
      int j = 2 * wv + jj;
      const unsigned short* g = A + (size_t)(bm + j * 8 + g_row8) * 512 + k0 + g_ck * 8;
      __builtin_amdgcn_global_load_lds(
          (const __attribute__((address_space(1))) unsigned int*)g,
          (__attribute__((address_space(3))) unsigned int*)(&As[j * 512 + l * 8]),
          16, 0, 0);
    }
    if (!fmode) {
      int row = bn + wv * 8 + g_row8;
      const unsigned short* g = (const unsigned short*)Bw + (size_t)row * 512 + k0 + g_ck * 8;
      __builtin_amdgcn_global_load_lds(
          (const __attribute__((address_space(1))) unsigned int*)g,
          (__attribute__((address_space(3))) unsigned int*)(&Bs[wv * 512 + l * 8]),
          16, 0, 0);
    } else {
      int row = t >> 3, cb = t & 7;     // 32 rows x 8 chunks
      const float* g = (const float*)Bw + (size_t)(bn + row) * 512 + k0 + cb * 8;
      unsigned short tb[8];
#pragma unroll
      for (int u = 0; u < 8; u++) tb[u] = f2bf(g[u]);
      int pc = cb ^ (row & 7);
      *(uint4*)&Bs[row * 64 + pc * 8] = *(const uint4*)tb;
    }
    __syncthreads();
#pragma unroll
    for (int kk = 0; kk < 64; kk += 32) {
      int c = (kk >> 3) + qd;
      short8 af = *(const short8*)&As[(wv * 16 + ln) * 64 + ((c ^ (ln & 7)) * 8)];
#pragma unroll
      for (int tj = 0; tj < 2; tj++) {
        short8 bf = *(const short8*)&Bs[(tj * 16 + ln) * 64 + ((c ^ (ln & 7)) * 8)];
        acc[tj] = __builtin_amdgcn_mfma_f32_16x16x32_bf16(af, bf, acc[tj], 0, 0, 0);
      }
    }
    __syncthreads();
  }
#pragma unroll
  for (int tj = 0; tj < 2; tj++) {
    int col = bn + tj * 16 + ln;
    float bv = biasf[col];
#pragma unroll
    for (int i = 0; i < 4; i++) {
      int row = bm + wv * 16 + qd * 4 + i;
      float v = acc[tj][i] + bv;
      if (fmode) ((float*)C)[(size_t)row * 512 + col] = v;
      else       ((unsigned short*)C)[(size_t)row * 512 + col] = f2bf(v);
    }
  }
}

// ---- attention core: 512 blocks x 32 m-rows, 39.9KB LDS (no v staging) ----
#define SST 132    // f32 per S row (pad); W bf16 overlays same rows (stride 264 u16)

__global__ __launch_bounds__(512) void k_attn(
    const unsigned short* __restrict__ XQ, const unsigned short* __restrict__ VT,
    const unsigned short* __restrict__ AT, const unsigned int* __restrict__ MB,
    const float* __restrict__ RBf, unsigned short* __restrict__ ATTO) {
  __shared__ __align__(16) float Sf[32 * SST];          // 16896 B
  __shared__ __align__(16) unsigned short qs[32][72];   // 4608
  __shared__ __align__(16) unsigned short ks[128][72];  // 18432
  unsigned short* Wb = (unsigned short*)Sf;

  // 512 blocks = (slot 0..63) x (xcd 0..7); m-quarter pinned to an XCD pair
  // -> per-L2 A_t hot set = 139 KB.
  const int i0 = blockIdx.x;
  const int xcd = i0 & 7, slot = i0 >> 3;
  const int mq = xcd >> 1;                 // 0..3 (32 m-rows each)
  const int bhid = slot * 2 + (xcd & 1);   // 0..127
  const int h = bhid & 7, b = bhid >> 3;
  const int bh = b * 8 + h;
  const int t = threadIdx.x;
  const int wv = t >> 6, l = t & 63, ln = l & 15, qd = l >> 4;

  // middle-section ids (also used for early A prefetch)
  const int ml = t >> 4, q16 = t & 15, n0 = q16 * 8;
  const int m = mq * 32 + ml;
  const unsigned short* abase = AT + (size_t)m * 128 + n0;
  // early prefetch: first A plane + mask bits issued before staging (cold-HBM
  // latency hides under the q/k staging + S-MFMA phases)
  uint4 ca = *(const uint4*)abase;
  const unsigned int mb = MB[m];

  // ---- staging: q(32x64), k(128x64) ----
  for (int it = t; it < 1280; it += 512) {
    int row = it >> 3, ck = it & 7;
    if (row < 32) {
      const unsigned short* g = XQ + (size_t)(b * 128 + mq * 32 + row) * 1024 + h * 64 + ck * 8;
      *(uint4*)&qs[row][ck * 8] = *(const uint4*)g;
    } else {
      int nr = row - 32;
      const unsigned short* g = XQ + (size_t)(b * 128 + nr) * 1024 + 512 + h * 64 + ck * 8;
      *(uint4*)&ks[nr][ck * 8] = *(const uint4*)g;
    }
  }
  __syncthreads();

  // ---- S(32x128) = q @ k^T * scale : 8 waves ----
  {
    f32x4 accS[2] = {};
    const int rt = wv & 1, ch = wv >> 1;
#pragma unroll
    for (int kk = 0; kk < 64; kk += 32) {
      short8 af = *(const short8*)&qs[rt * 16 + ln][kk + qd * 8];
#pragma unroll
      for (int tj = 0; tj < 2; tj++) {
        short8 bf = *(const short8*)&ks[ch * 32 + tj * 16 + ln][kk + qd * 8];
        accS[tj] = __builtin_amdgcn_mfma_f32_16x16x32_bf16(af, bf, accS[tj], 0, 0, 0);
      }
    }
#pragma unroll
    for (int tj = 0; tj < 2; tj++)
#pragma unroll
      for (int i = 0; i < 4; i++)
        Sf[(rt * 16 + qd * 4 + i) * SST + ch * 32 + tj * 16 + ln] =
            accS[tj][i] * 0.125f;
  }
  __syncthreads();

  // ---- fused single-pass logits+softmax+W : 16 thr/row x 8 n-values ----
  // max-free softmax: logits O(10) << 88 (fp32 exp limit); dividing by the sum
  // afterwards is mathematically identical to ref softmax.
  {
    float sreg[8];
#pragma unroll
    for (int c4 = 0; c4 < 2; c4++) {
      float4 s4 = *(const float4*)&Sf[ml * SST + n0 + c4 * 4];
      sreg[c4 * 4 + 0] = s4.x; sreg[c4 * 4 + 1] = s4.y;
      sreg[c4 * 4 + 2] = s4.z; sreg[c4 * 4 + 3] = s4.w;
    }
    float wacc[8];
#pragma unroll
    for (int j = 0; j < 8; j++) wacc[j] = 0.0f;
    float sum = 0.0f;
#pragma unroll
    for (int r = 0; r < 17; r++) {
      uint4 na;
      if (r + 1 < 17) na = *(const uint4*)(abase + (r + 1) * 16384);
      float av[8];
      const unsigned short* a8 = (const unsigned short*)&ca;
#pragma unroll
      for (int j = 0; j < 8; j++) av[j] = bf2f(a8[j]);
      float s = 0.0f;
#pragma unroll
      for (int j = 0; j < 8; j++) s += sreg[j] * av[j];
      s += __shfl_xor(s, 1);
      s += __shfl_xor(s, 2);
      s += __shfl_xor(s, 4);
      s += __shfl_xor(s, 8);
      float e = ((mb >> r) & 1) ? 0.0f : __expf(s + RBf[h * 17 + r]);
      sum += e;
#pragma unroll
      for (int j = 0; j < 8; j++) wacc[j] += e * av[j];
      ca = na;
    }
    const float inv = 1.0f / sum;
    unsigned short pk[8];
#pragma unroll
    for (int j = 0; j < 8; j++) pk[j] = f2bf(wacc[j] * inv);
    // W overlays same-row S bytes; the row's 16 threads are consecutive lanes
    // of one wave and all S reads precede these writes in program order
    *(uint4*)&Wb[ml * 264 + n0] = *(const uint4*)&pk[0];
  }
  __syncthreads();

  // ---- out(32x64) = W(32x128) @ v(128x64) : v^T fragments from L2 ----
  {
    f32x4 accO = {};
    const int rt = wv & 1, dt = wv >> 1;
    const int d = dt * 16 + ln;
    const unsigned short* vrow = VT + ((size_t)bh * 64 + d) * 128;
#pragma unroll
    for (int kk = 0; kk < 128; kk += 32) {
      short8 af = *(const short8*)&Wb[(rt * 16 + ln) * 264 + kk + qd * 8];
      short8 bf = *(const short8*)(vrow + kk + qd * 8);
      accO = __builtin_amdgcn_mfma_f32_16x16x32_bf16(af, bf, accO, 0, 0, 0);
    }
#pragma unroll
    for (int i = 0; i < 4; i++) {
      int row = b * 128 + mq * 32 + rt * 16 + qd * 4 + i;
      ATTO[(size_t)row * 512 + h * 64 + d] = f2bf(accO[i]);
    }
  }
}

extern "C" void kernel_launch(void* const* d_in, const int* in_sizes, int n_in,
                              void* d_out, int out_size, void* d_ws, size_t ws_size,
                              hipStream_t stream) {
  unsigned char* ws = (unsigned char*)d_ws;
  // 0:x 1:assignment 2:mask 3:q_w 4:kv_w 5:rel_bias 6:proj_w 7:proj_b
  k_phase1<<<896, 256, 0, stream>>>(d_in[0], d_in[3], d_in[4], d_in[1],
                                    (const unsigned char*)d_in[2],
                                    d_in[5], d_in[7], ws);
  k_attn<<<512, 512, 0, stream>>>((const unsigned short*)(ws + OFF_XQ),
                                  (const unsigned short*)(ws + OFF_VT),
                                  (const unsigned short*)(ws + OFF_AT),
                                  (const unsigned int*)(ws + OFF_MB),
                                  (const float*)(ws + OFF_RBF),
                                  (unsigned short*)(ws + OFF_ATTO));
  k_proj<<<dim3(32, 16), 256, 0, stream>>>((const unsigned short*)(ws + OFF_ATTO),
                                           d_in[6],
                                           (const float*)(ws + OFF_PBF),
                                           (const int*)ws, d_out);
}

// Round 13
// 114.364 us; speedup vs baseline: 1.2640x; 1.0021x over previous
//
#include <hip/hip_runtime.h>
#include <cstdint>
#include <cstddef>

#define DI __device__ __forceinline__

typedef __attribute__((ext_vector_type(8))) short short8;
typedef __attribute__((ext_vector_type(4))) float f32x4;

DI float bf2f(unsigned short u) {
  union { unsigned int i; float f; } c; c.i = ((unsigned int)u) << 16; return c.f;
}
DI unsigned short f2bf(float f) {
  union { float fl; unsigned int i; } c; c.fl = f;
  return (unsigned short)((c.i + 0x7FFFu + ((c.i >> 16) & 1u)) >> 16);
}

// ---- workspace layout (bytes) ----
static const size_t OFF_MB   = 256;                       // u32[128] mask bitwords
static const size_t OFF_RBF  = 1024;                      // f32[136] rel_bias
static const size_t OFF_PBF  = 2048;                      // f32[512] proj_b
static const size_t OFF_AT   = 16384;                     // bf16 A_t[17][128][128]
static const size_t OFF_XQ   = OFF_AT + 557056;           // bf16 [2048][1024] (q|k)
static const size_t OFF_VT   = OFF_XQ + (size_t)4194304;  // bf16 [128bh][64d][128n]
static const size_t OFF_ATTO = OFF_VT + (size_t)2097152;  // bf16 [2048][512]

// ---- phase1: blocks 0..767 qkv GEMM (64x64 tile, 3 blocks/CU); 768..895 prep ----
__global__ __launch_bounds__(256) void k_phase1(
    const void* __restrict__ x, const void* __restrict__ qw,
    const void* __restrict__ kvw, const void* __restrict__ as,
    const unsigned char* __restrict__ mr, const void* __restrict__ rb,
    const void* __restrict__ pb, unsigned char* __restrict__ ws) {
  __shared__ unsigned short As[64 * 64];
  __shared__ unsigned short Bs[64 * 64];
  __shared__ int s_c0, s_3f, s_b1, s_odd;
  const int t = threadIdx.x;
  const int blk = blockIdx.x;

  if (t == 0) { s_c0 = 0; s_3f = 0; s_b1 = 0; s_odd = 0; }
  __syncthreads();
  // fmode self-detect (every block; 256B of x prefix, L2-broadcast after first)
  if (t < 128) {
    unsigned short u = ((const unsigned short*)x)[2 * t];
    int e = (u >> 7) & 0xFF;
    if (e >= 64 && e <= 150) atomicAdd(&s_c0, 1);
  }

  if (blk < 768) {
    // ============ qkv GEMM: C[2048,1536] = x @ [qw;kvw]^T, 64x64 tile ============
    __syncthreads();
    const int fmode = (s_c0 >= 96) ? 0 : 1;
    const int bm = (blk & 31) * 64, bn = (blk >> 5) * 64;
    const int wv = t >> 6, l = t & 63, ln = l & 15, qd = l >> 4;
    f32x4 acc[4] = {};
    const int g_row8 = l >> 3;
    const int g_ck = (l & 7) ^ g_row8;
    const int s_row = t >> 2;
    const int s_cb = (t & 3) * 2;
    for (int k0 = 0; k0 < 512; k0 += 64) {
      if (!fmode) {
        const unsigned short* xb = (const unsigned short*)x;
#pragma unroll
        for (int jj = 0; jj < 2; jj++) {
          int j = 2 * wv + jj;
          const unsigned short* g = xb + (size_t)(bm + j * 8 + g_row8) * 512 + k0 + g_ck * 8;
          __builtin_amdgcn_global_load_lds(
              (const __attribute__((address_space(1))) unsigned int*)g,
              (__attribute__((address_space(3))) unsigned int*)(&As[j * 512 + l * 8]),
              16, 0, 0);
        }
#pragma unroll
        for (int jj = 0; jj < 2; jj++) {
          int j = 2 * wv + jj;
          int row = bn + j * 8 + g_row8;
          const unsigned short* base = (row < 512)
              ? (const unsigned short*)qw + (size_t)row * 512
              : (const unsigned short*)kvw + (size_t)(row - 512) * 512;
          const unsigned short* g = base + k0 + g_ck * 8;
          __builtin_amdgcn_global_load_lds(
              (const __attribute__((address_space(1))) unsigned int*)g,
              (__attribute__((address_space(3))) unsigned int*)(&Bs[j * 512 + l * 8]),
              16, 0, 0);
        }
      } else {
        const float* ga = (const float*)x + (size_t)(bm + s_row) * 512 + k0 + s_cb * 8;
        int brow = bn + s_row;
        const float* gb = ((brow < 512) ? (const float*)qw + (size_t)brow * 512
                                        : (const float*)kvw + (size_t)(brow - 512) * 512)
                          + k0 + s_cb * 8;
#pragma unroll
        for (int cc = 0; cc < 2; cc++) {
          unsigned short ta[8], tb[8];
#pragma unroll
          for (int u = 0; u < 8; u++) { ta[u] = f2bf(ga[cc * 8 + u]); tb[u] = f2bf(gb[cc * 8 + u]); }
          int pc = (s_cb + cc) ^ (s_row & 7);
          *(uint4*)&As[s_row * 64 + pc * 8] = *(const uint4*)ta;
          *(uint4*)&Bs[s_row * 64 + pc * 8] = *(const uint4*)tb;
        }
      }
      __syncthreads();
#pragma unroll
      for (int kk = 0; kk < 64; kk += 32) {
        int c = (kk >> 3) + qd;
        short8 af = *(const short8*)&As[(wv * 16 + ln) * 64 + ((c ^ (ln & 7)) * 8)];
#pragma unroll
        for (int tj = 0; tj < 4; tj++) {
          short8 bf = *(const short8*)&Bs[(tj * 16 + ln) * 64 + ((c ^ (ln & 7)) * 8)];
          acc[tj] = __builtin_amdgcn_mfma_f32_16x16x32_bf16(af, bf, acc[tj], 0, 0, 0);
        }
      }
      __syncthreads();
    }
    unsigned short* XQ = (unsigned short*)(ws + OFF_XQ);
    unsigned short* VT = (unsigned short*)(ws + OFF_VT);
#pragma unroll
    for (int tj = 0; tj < 4; tj++) {
      int col = bn + tj * 16 + ln;
      if (col >= 1024) {                       // V -> transposed, packed 8B store
        int c1 = col - 1024;
        int row0 = bm + wv * 16 + qd * 4;
        int bh = (row0 >> 7) * 8 + (c1 >> 6);
        ushort4 pk;
        pk.x = f2bf(acc[tj][0]); pk.y = f2bf(acc[tj][1]);
        pk.z = f2bf(acc[tj][2]); pk.w = f2bf(acc[tj][3]);
        *(ushort4*)&VT[((size_t)bh * 64 + (c1 & 63)) * 128 + (row0 & 127)] = pk;
      } else {
#pragma unroll
        for (int i = 0; i < 4; i++) {
          int row = bm + wv * 16 + qd * 4 + i;
          XQ[(size_t)row * 1024 + col] = f2bf(acc[tj][i]);
        }
      }
    }
  } else {
    // ================= prep: A_t repack + mask bits + biases =================
    {
      int f3 = 0, b1 = 0, od = 0;
      for (int i = t; i < 2176; i += 256) {
        unsigned char bb = mr[i];
        if (bb == 0x3F) f3 = 1;
        if (bb) { if ((i & 3) == 1) b1 = 1; if (i & 3) od = 1; }
      }
      if (f3) atomicOr(&s_3f, 1);
      if (b1) atomicOr(&s_b1, 1);
      if (od) atomicOr(&s_odd, 1);
    }
    __syncthreads();
    const int fmode = (s_c0 >= 96) ? 0 : 1;
    const int mmode = s_3f ? (s_b1 ? 2 : 3) : (s_odd ? 0 : 1);
    const int gid = (blk - 768) * 256 + t;
    if (gid == 0) { ((int*)ws)[0] = fmode; ((int*)ws)[1] = mmode; }
    unsigned short* At = (unsigned short*)(ws + OFF_AT);
    unsigned int* MB = (unsigned int*)(ws + OFF_MB);
    float* RBf = (float*)(ws + OFF_RBF);
    float* PBf = (float*)(ws + OFF_PBF);
    const int gs = 128 * 256;
    for (int i = gid; i < 279304; i += gs) {
      if (i < 278528) {
        int r = i >> 14, mn = i & 16383;
        int si = mn * 17 + r;
        At[i] = fmode ? f2bf(((const float*)as)[si]) : ((const unsigned short*)as)[si];
      } else if (i < 278656) {
        int m = i - 278528;
        unsigned int bits = 0;
        for (int r = 0; r < 17; r++) {
          int j = m * 17 + r, v;
          if (mmode == 0)      v = mr[j] != 0;
          else if (mmode == 1) v = ((const int*)mr)[j] != 0;
          else if (mmode == 2) v = ((const unsigned short*)mr)[j] != 0;
          else                 v = ((const float*)mr)[j] != 0.0f;
          bits |= (unsigned int)v << r;
        }
        MB[m] = bits;
      } else if (i < 278792) {
        int j = i - 278656;
        RBf[j] = fmode ? ((const float*)rb)[j] : bf2f(((const unsigned short*)rb)[j]);
      } else {
        int j = i - 278792;
        PBf[j] = fmode ? ((const float*)pb)[j] : bf2f(((const unsigned short*)pb)[j]);
      }
    }
  }
}

// ---- proj GEMM: 64x32 tiles, 512 blocks (~2-3/CU) ----
__global__ __launch_bounds__(256) void k_proj(
    const unsigned short* __restrict__ A,   // ATTO bf16 [2048][512]
    const void* __restrict__ Bw,            // proj_w raw
    const float* __restrict__ biasf,
    const int* __restrict__ flags, void* __restrict__ C) {
  __shared__ unsigned short As[64 * 64];
  __shared__ unsigned short Bs[32 * 64];
  const int fmode = flags[0];
  const int bm = blockIdx.x * 64, bn = blockIdx.y * 32;
  const int t = threadIdx.x, wv = t >> 6, l = t & 63, ln = l & 15, qd = l >> 4;
  f32x4 acc[2] = {};
  const int g_row8 = l >> 3;
  const int g_ck = (l & 7) ^ g_row8;
  for (int k0 = 0; k0 < 512; k0 += 64) {
    // A: always bf16 (internal), 2 glld per wave
#pragma unroll
    for (int jj = 0; jj < 2; jj++) {
      int j = 2 * wv + jj;
      const unsigned short* g = A + (size_t)(bm + j * 8 + g_row8) * 512 + k0 + g_ck * 8;
      __builtin_amdgcn_global_load_lds(
          (const __attribute__((address_space(1))) unsigned int*)g,
          (__attribute__((address_space(3))) unsigned int*)(&As[j * 512 + l * 8]),
          16, 0, 0);
    }
    if (!fmode) {
      int row = bn + wv * 8 + g_row8;
      const unsigned short* g = (const unsigned short*)Bw + (size_t)row * 512 + k0 + g_ck * 8;
      __builtin_amdgcn_global_load_lds(
          (const __attribute__((address_space(1))) unsigned int*)g,
          (__attribute__((address_space(3))) unsigned int*)(&Bs[wv * 512 + l * 8]),
          16, 0, 0);
    } else {
      int row = t >> 3, cb = t & 7;     // 32 rows x 8 chunks
      const float* g = (const float*)Bw + (size_t)(bn + row) * 512 + k0 + cb * 8;
      unsigned short tb[8];
#pragma unroll
      for (int u = 0; u < 8; u++) tb[u] = f2bf(g[u]);
      int pc = cb ^ (row & 7);
      *(uint4*)&Bs[row * 64 + pc * 8] = *(const uint4*)tb;
    }
    __syncthreads();
#pragma unroll
    for (int kk = 0; kk < 64; kk += 32) {
      int c = (kk >> 3) + qd;
      short8 af = *(const short8*)&As[(wv * 16 + ln) * 64 + ((c ^ (ln & 7)) * 8)];
#pragma unroll
      for (int tj = 0; tj < 2; tj++) {
        short8 bf = *(const short8*)&Bs[(tj * 16 + ln) * 64 + ((c ^ (ln & 7)) * 8)];
        acc[tj] = __builtin_amdgcn_mfma_f32_16x16x32_bf16(af, bf, acc[tj], 0, 0, 0);
      }
    }
    __syncthreads();
  }
#pragma unroll
  for (int tj = 0; tj < 2; tj++) {
    int col = bn + tj * 16 + ln;
    float bv = biasf[col];
#pragma unroll
    for (int i = 0; i < 4; i++) {
      int row = bm + wv * 16 + qd * 4 + i;
      float v = acc[tj][i] + bv;
      if (fmode) ((float*)C)[(size_t)row * 512 + col] = v;
      else       ((unsigned short*)C)[(size_t)row * 512 + col] = f2bf(v);
    }
  }
}

// ---- attention core: 512 blocks x 32 m-rows, 39.9KB LDS (no v staging) ----
#define SST 132    // f32 per S row (pad); W bf16 overlays same rows (stride 264 u16)

__global__ __launch_bounds__(512) void k_attn(
    const unsigned short* __restrict__ XQ, const unsigned short* __restrict__ VT,
    const unsigned short* __restrict__ AT, const unsigned int* __restrict__ MB,
    const float* __restrict__ RBf, unsigned short* __restrict__ ATTO) {
  __shared__ __align__(16) float Sf[32 * SST];          // 16896 B
  __shared__ __align__(16) unsigned short qs[32][72];   // 4608
  __shared__ __align__(16) unsigned short ks[128][72];  // 18432
  unsigned short* Wb = (unsigned short*)Sf;

  // 512 blocks = (slot 0..63) x (xcd 0..7); m-quarter pinned to an XCD pair
  // -> per-L2 A_t hot set = 139 KB.
  const int i0 = blockIdx.x;
  const int xcd = i0 & 7, slot = i0 >> 3;
  const int mq = xcd >> 1;                 // 0..3 (32 m-rows each)
  const int bhid = slot * 2 + (xcd & 1);   // 0..127
  const int h = bhid & 7, b = bhid >> 3;
  const int bh = b * 8 + h;
  const int t = threadIdx.x;
  const int wv = t >> 6, l = t & 63, ln = l & 15, qd = l >> 4;

  // middle-section ids (also used for early A prefetch)
  const int ml = t >> 4, q16 = t & 15, n0 = q16 * 8;
  const int m = mq * 32 + ml;
  const unsigned short* abase = AT + (size_t)m * 128 + n0;
  // early prefetch: first A plane + mask bits issued before staging (cold-HBM
  // latency hides under the q/k staging + S-MFMA phases)
  uint4 ca = *(const uint4*)abase;
  const unsigned int mb = MB[m];

  // ---- staging: q(32x64), k(128x64) ----
  for (int it = t; it < 1280; it += 512) {
    int row = it >> 3, ck = it & 7;
    if (row < 32) {
      const unsigned short* g = XQ + (size_t)(b * 128 + mq * 32 + row) * 1024 + h * 64 + ck * 8;
      *(uint4*)&qs[row][ck * 8] = *(const uint4*)g;
    } else {
      int nr = row - 32;
      const unsigned short* g = XQ + (size_t)(b * 128 + nr) * 1024 + 512 + h * 64 + ck * 8;
      *(uint4*)&ks[nr][ck * 8] = *(const uint4*)g;
    }
  }
  __syncthreads();

  // ---- S(32x128) = q @ k^T * scale : 8 waves ----
  {
    f32x4 accS[2] = {};
    const int rt = wv & 1, ch = wv >> 1;
#pragma unroll
    for (int kk = 0; kk < 64; kk += 32) {
      short8 af = *(const short8*)&qs[rt * 16 + ln][kk + qd * 8];
#pragma unroll
      for (int tj = 0; tj < 2; tj++) {
        short8 bf = *(const short8*)&ks[ch * 32 + tj * 16 + ln][kk + qd * 8];
        accS[tj] = __builtin_amdgcn_mfma_f32_16x16x32_bf16(af, bf, accS[tj], 0, 0, 0);
      }
    }
#pragma unroll
    for (int tj = 0; tj < 2; tj++)
#pragma unroll
      for (int i = 0; i < 4; i++)
        Sf[(rt * 16 + qd * 4 + i) * SST + ch * 32 + tj * 16 + ln] =
            accS[tj][i] * 0.125f;
  }
  __syncthreads();

  // ---- fused single-pass logits+softmax+W : 16 thr/row x 8 n-values ----
  // max-free softmax: logits O(10) << 88 (fp32 exp limit); dividing by the sum
  // afterwards is mathematically identical to ref softmax.
  {
    float sreg[8];
#pragma unroll
    for (int c4 = 0; c4 < 2; c4++) {
      float4 s4 = *(const float4*)&Sf[ml * SST + n0 + c4 * 4];
      sreg[c4 * 4 + 0] = s4.x; sreg[c4 * 4 + 1] = s4.y;
      sreg[c4 * 4 + 2] = s4.z; sreg[c4 * 4 + 3] = s4.w;
    }
    float wacc[8];
#pragma unroll
    for (int j = 0; j < 8; j++) wacc[j] = 0.0f;
    float sum = 0.0f;
#pragma unroll
    for (int r = 0; r < 17; r++) {
      uint4 na;
      if (r + 1 < 17) na = *(const uint4*)(abase + (r + 1) * 16384);
      float av[8];
      const unsigned short* a8 = (const unsigned short*)&ca;
#pragma unroll
      for (int j = 0; j < 8; j++) av[j] = bf2f(a8[j]);
      float s = 0.0f;
#pragma unroll
      for (int j = 0; j < 8; j++) s += sreg[j] * av[j];
      s += __shfl_xor(s, 1);
      s += __shfl_xor(s, 2);
      s += __shfl_xor(s, 4);
      s += __shfl_xor(s, 8);
      float e = ((mb >> r) & 1) ? 0.0f : __expf(s + RBf[h * 17 + r]);
      sum += e;
#pragma unroll
      for (int j = 0; j < 8; j++) wacc[j] += e * av[j];
      ca = na;
    }
    const float inv = 1.0f / sum;
    unsigned short pk[8];
#pragma unroll
    for (int j = 0; j < 8; j++) pk[j] = f2bf(wacc[j] * inv);
    // W overlays same-row S bytes; the row's 16 threads are consecutive lanes
    // of one wave and all S reads precede these writes in program order
    *(uint4*)&Wb[ml * 264 + n0] = *(const uint4*)&pk[0];
  }
  __syncthreads();

  // ---- out(32x64) = W(32x128) @ v(128x64) : v^T fragments from L2 ----
  {
    f32x4 accO = {};
    const int rt = wv & 1, dt = wv >> 1;
    const int d = dt * 16 + ln;
    const unsigned short* vrow = VT + ((size_t)bh * 64 + d) * 128;
#pragma unroll
    for (int kk = 0; kk < 128; kk += 32) {
      short8 af = *(const short8*)&Wb[(rt * 16 + ln) * 264 + kk + qd * 8];
      short8 bf = *(const short8*)(vrow + kk + qd * 8);
      accO = __builtin_amdgcn_mfma_f32_16x16x32_bf16(af, bf, accO, 0, 0, 0);
    }
#pragma unroll
    for (int i = 0; i < 4; i++) {
      int row = b * 128 + mq * 32 + rt * 16 + qd * 4 + i;
      ATTO[(size_t)row * 512 + h * 64 + d] = f2bf(accO[i]);
    }
  }
}

extern "C" void kernel_launch(void* const* d_in, const int* in_sizes, int n_in,
                              void* d_out, int out_size, void* d_ws, size_t ws_size,
                              hipStream_t stream) {
  unsigned char* ws = (unsigned char*)d_ws;
  // 0:x 1:assignment 2:mask 3:q_w 4:kv_w 5:rel_bias 6:proj_w 7:proj_b
  k_phase1<<<896, 256, 0, stream>>>(d_in[0], d_in[3], d_in[4], d_in[1],
                                    (const unsigned char*)d_in[2],
                                    d_in[5], d_in[7], ws);
  k_attn<<<512, 512, 0, stream>>>((const unsigned short*)(ws + OFF_XQ),
                                  (const unsigned short*)(ws + OFF_VT),
                                  (const unsigned short*)(ws + OFF_AT),
                                  (const unsigned int*)(ws + OFF_MB),
                                  (const float*)(ws + OFF_RBF),
                                  (unsigned short*)(ws + OFF_ATTO));
  k_proj<<<dim3(32, 16), 256, 0, stream>>>((const unsigned short*)(ws + OFF_ATTO),
                                           d_in[6],
                                           (const float*)(ws + OFF_PBF),
                                           (const int*)ws, d_out);
}

// Round 14
// 112.923 us; speedup vs baseline: 1.2802x; 1.0128x over previous
//
#include <hip/hip_runtime.h>
#include <cstdint>
#include <cstddef>

#define DI __device__ __forceinline__

typedef __attribute__((ext_vector_type(8))) short short8;
typedef __attribute__((ext_vector_type(4))) float f32x4;

DI float bf2f(unsigned short u) {
  union { unsigned int i; float f; } c; c.i = ((unsigned int)u) << 16; return c.f;
}
DI unsigned short f2bf(float f) {
  union { float fl; unsigned int i; } c; c.fl = f;
  return (unsigned short)((c.i + 0x7FFFu + ((c.i >> 16) & 1u)) >> 16);
}

// ---- workspace layout (bytes) ----
static const size_t OFF_MB   = 256;                       // u32[128] mask bitwords
static const size_t OFF_RBF  = 1024;                      // f32[136] rel_bias
static const size_t OFF_PBF  = 2048;                      // f32[512] proj_b
static const size_t OFF_AT   = 16384;                     // bf16 A_t[17][128][128]
static const size_t OFF_XQ   = OFF_AT + 557056;           // bf16 [2048][1024] (q|k)
static const size_t OFF_VT   = OFF_XQ + (size_t)4194304;  // bf16 [128bh][64d][128n]
static const size_t OFF_ATTO = OFF_VT + (size_t)2097152;  // bf16 [2048][512]

// ---- phase1: blocks 0..127 prep (dispatch-first => starts early);
//              blocks 128..895 qkv GEMM (64x64 tile, ~3 blocks/CU) ----
__global__ __launch_bounds__(256) void k_phase1(
    const void* __restrict__ x, const void* __restrict__ qw,
    const void* __restrict__ kvw, const void* __restrict__ as,
    const unsigned char* __restrict__ mr, const void* __restrict__ rb,
    const void* __restrict__ pb, unsigned char* __restrict__ ws) {
  __shared__ unsigned short As[64 * 64];
  __shared__ unsigned short Bs[64 * 64];
  __shared__ int s_c0, s_3f, s_b1, s_odd;
  const int t = threadIdx.x;
  const int blk = blockIdx.x;

  if (t == 0) { s_c0 = 0; s_3f = 0; s_b1 = 0; s_odd = 0; }
  __syncthreads();
  // fmode self-detect (every block; 256B of x prefix, L2-broadcast after first)
  if (t < 128) {
    unsigned short u = ((const unsigned short*)x)[2 * t];
    int e = (u >> 7) & 0xFF;
    if (e >= 64 && e <= 150) atomicAdd(&s_c0, 1);
  }

  if (blk < 128) {
    // ============ prep: A_t repack via coalesced LDS transpose ============
    {
      int f3 = 0, b1 = 0, od = 0;
      for (int i = t; i < 2176; i += 256) {
        unsigned char bb = mr[i];
        if (bb == 0x3F) f3 = 1;
        if (bb) { if ((i & 3) == 1) b1 = 1; if (i & 3) od = 1; }
      }
      if (f3) atomicOr(&s_3f, 1);
      if (b1) atomicOr(&s_b1, 1);
      if (od) atomicOr(&s_odd, 1);
    }
    __syncthreads();
    const int fmode = (s_c0 >= 96) ? 0 : 1;
    const int mmode = s_3f ? (s_b1 ? 2 : 3) : (s_odd ? 0 : 1);
    unsigned short* At = (unsigned short*)(ws + OFF_AT);
    float* sL = (float*)As;                 // 1088 f32 = 4352 B staging
    // 128 mn-rows per block, 2 groups of 64: coalesced read -> LDS -> coalesced write
    for (int gi = 0; gi < 2; gi++) {
      int mn0 = blk * 128 + gi * 64;
      for (int j = t; j < 1088; j += 256)
        sL[j] = fmode ? ((const float*)as)[(size_t)mn0 * 17 + j]
                      : bf2f(((const unsigned short*)as)[(size_t)mn0 * 17 + j]);
      __syncthreads();
      for (int w = t; w < 1088; w += 256) {
        int r = w >> 6, jj = w & 63;
        At[(size_t)r * 16384 + mn0 + jj] = f2bf(sL[jj * 17 + r]);
      }
      __syncthreads();
    }
    if (blk == 0) {
      if (t == 0) { ((int*)ws)[0] = fmode; ((int*)ws)[1] = mmode; }
      unsigned int* MB = (unsigned int*)(ws + OFF_MB);
      float* RBf = (float*)(ws + OFF_RBF);
      float* PBf = (float*)(ws + OFF_PBF);
      if (t < 128) {
        unsigned int bits = 0;
        for (int r = 0; r < 17; r++) {
          int j = t * 17 + r, v;
          if (mmode == 0)      v = mr[j] != 0;
          else if (mmode == 1) v = ((const int*)mr)[j] != 0;
          else if (mmode == 2) v = ((const unsigned short*)mr)[j] != 0;
          else                 v = ((const float*)mr)[j] != 0.0f;
          bits |= (unsigned int)v << r;
        }
        MB[t] = bits;
      }
      for (int j = t; j < 136; j += 256)
        RBf[j] = fmode ? ((const float*)rb)[j] : bf2f(((const unsigned short*)rb)[j]);
      for (int j = t; j < 512; j += 256)
        PBf[j] = fmode ? ((const float*)pb)[j] : bf2f(((const unsigned short*)pb)[j]);
    }
  } else {
    // ============ qkv GEMM: C[2048,1536] = x @ [qw;kvw]^T, 64x64 tile ============
    __syncthreads();
    const int fmode = (s_c0 >= 96) ? 0 : 1;
    const int gb2 = blk - 128;
    const int bm = (gb2 & 31) * 64, bn = (gb2 >> 5) * 64;
    const int wv = t >> 6, l = t & 63, ln = l & 15, qd = l >> 4;
    f32x4 acc[4] = {};
    const int g_row8 = l >> 3;
    const int g_ck = (l & 7) ^ g_row8;
    const int s_row = t >> 2;
    const int s_cb = (t & 3) * 2;
    for (int k0 = 0; k0 < 512; k0 += 64) {
      if (!fmode) {
        const unsigned short* xb = (const unsigned short*)x;
#pragma unroll
        for (int jj = 0; jj < 2; jj++) {
          int j = 2 * wv + jj;
          const unsigned short* g = xb + (size_t)(bm + j * 8 + g_row8) * 512 + k0 + g_ck * 8;
          __builtin_amdgcn_global_load_lds(
              (const __attribute__((address_space(1))) unsigned int*)g,
              (__attribute__((address_space(3))) unsigned int*)(&As[j * 512 + l * 8]),
              16, 0, 0);
        }
#pragma unroll
        for (int jj = 0; jj < 2; jj++) {
          int j = 2 * wv + jj;
          int row = bn + j * 8 + g_row8;
          const unsigned short* base = (row < 512)
              ? (const unsigned short*)qw + (size_t)row * 512
              : (const unsigned short*)kvw + (size_t)(row - 512) * 512;
          const unsigned short* g = base + k0 + g_ck * 8;
          __builtin_amdgcn_global_load_lds(
              (const __attribute__((address_space(1))) unsigned int*)g,
              (__attribute__((address_space(3))) unsigned int*)(&Bs[j * 512 + l * 8]),
              16, 0, 0);
        }
      } else {
        const float* ga = (const float*)x + (size_t)(bm + s_row) * 512 + k0 + s_cb * 8;
        int brow = bn + s_row;
        const float* gb = ((brow < 512) ? (const float*)qw + (size_t)brow * 512
                                        : (const float*)kvw + (size_t)(brow - 512) * 512)
                          + k0 + s_cb * 8;
#pragma unroll
        for (int cc = 0; cc < 2; cc++) {
          unsigned short ta[8], tb[8];
#pragma unroll
          for (int u = 0; u < 8; u++) { ta[u] = f2bf(ga[cc * 8 + u]); tb[u] = f2bf(gb[cc * 8 + u]); }
          int pc = (s_cb + cc) ^ (s_row & 7);
          *(uint4*)&As[s_row * 64 + pc * 8] = *(const uint4*)ta;
          *(uint4*)&Bs[s_row * 64 + pc * 8] = *(const uint4*)tb;
        }
      }
      __syncthreads();
#pragma unroll
      for (int kk = 0; kk < 64; kk += 32) {
        int c = (kk >> 3) + qd;
        short8 af = *(const short8*)&As[(wv * 16 + ln) * 64 + ((c ^ (ln & 7)) * 8)];
#pragma unroll
        for (int tj = 0; tj < 4; tj++) {
          short8 bf = *(const short8*)&Bs[(tj * 16 + ln) * 64 + ((c ^ (ln & 7)) * 8)];
          acc[tj] = __builtin_amdgcn_mfma_f32_16x16x32_bf16(af, bf, acc[tj], 0, 0, 0);
        }
      }
      __syncthreads();
    }
    unsigned short* XQ = (unsigned short*)(ws + OFF_XQ);
    unsigned short* VT = (unsigned short*)(ws + OFF_VT);
#pragma unroll
    for (int tj = 0; tj < 4; tj++) {
      int col = bn + tj * 16 + ln;
      if (col >= 1024) {                       // V -> transposed, packed 8B store
        int c1 = col - 1024;
        int row0 = bm + wv * 16 + qd * 4;
        int bh = (row0 >> 7) * 8 + (c1 >> 6);
        ushort4 pk;
        pk.x = f2bf(acc[tj][0]); pk.y = f2bf(acc[tj][1]);
        pk.z = f2bf(acc[tj][2]); pk.w = f2bf(acc[tj][3]);
        *(ushort4*)&VT[((size_t)bh * 64 + (c1 & 63)) * 128 + (row0 & 127)] = pk;
      } else {
#pragma unroll
        for (int i = 0; i < 4; i++) {
          int row = bm + wv * 16 + qd * 4 + i;
          XQ[(size_t)row * 1024 + col] = f2bf(acc[tj][i]);
        }
      }
    }
  }
}

// ---- proj GEMM: 64x32 tiles, 512 blocks (~2-3/CU) ----
__global__ __launch_bounds__(256) void k_proj(
    const unsigned short* __restrict__ A,   // ATTO bf16 [2048][512]
    const void* __restrict__ Bw,            // proj_w raw
    const float* __restrict__ biasf,
    const int* __restrict__ flags, void* __restrict__ C) {
  __shared__ unsigned short As[64 * 64];
  __shared__ unsigned short Bs[32 * 64];
  const int fmode = flags[0];
  const int bm = blockIdx.x * 64, bn = blockIdx.y * 32;
  const int t = threadIdx.x, wv = t >> 6, l = t & 63, ln = l & 15, qd = l >> 4;
  f32x4 acc[2] = {};
  const int g_row8 = l >> 3;
  const int g_ck = (l & 7) ^ g_row8;
  for (int k0 = 0; k0 < 512; k0 += 64) {
#pragma unroll
    for (int jj = 0; jj < 2; jj++) {
      int j = 2 * wv + jj;
      const unsigned short* g = A + (size_t)(bm + j * 8 + g_row8) * 512 + k0 + g_ck * 8;
      __builtin_amdgcn_global_load_lds(
          (const __attribute__((address_space(1))) unsigned int*)g,
          (__attribute__((address_space(3))) unsigned int*)(&As[j * 512 + l * 8]),
          16, 0, 0);
    }
    if (!fmode) {
      int row = bn + wv * 8 + g_row8;
      const unsigned short* g = (const unsigned short*)Bw + (size_t)row * 512 + k0 + g_ck * 8;
      __builtin_amdgcn_global_load_lds(
          (const __attribute__((address_space(1))) unsigned int*)g,
          (__attribute__((address_space(3))) unsigned int*)(&Bs[wv * 512 + l * 8]),
          16, 0, 0);
    } else {
      int row = t >> 3, cb = t & 7;     // 32 rows x 8 chunks
      const float* g = (const float*)Bw + (size_t)(bn + row) * 512 + k0 + cb * 8;
      unsigned short tb[8];
#pragma unroll
      for (int u = 0; u < 8; u++) tb[u] = f2bf(g[u]);
      int pc = cb ^ (row & 7);
      *(uint4*)&Bs[row * 64 + pc * 8] = *(const uint4*)tb;
    }
    __syncthreads();
#pragma unroll
    for (int kk = 0; kk < 64; kk += 32) {
      int c = (kk >> 3) + qd;
      short8 af = *(const short8*)&As[(wv * 16 + ln) * 64 + ((c ^ (ln & 7)) * 8)];
#pragma unroll
      for (int tj = 0; tj < 2; tj++) {
        short8 bf = *(const short8*)&Bs[(tj * 16 + ln) * 64 + ((c ^ (ln & 7)) * 8)];
        acc[tj] = __builtin_amdgcn_mfma_f32_16x16x32_bf16(af, bf, acc[tj], 0, 0, 0);
      }
    }
    __syncthreads();
  }
#pragma unroll
  for (int tj = 0; tj < 2; tj++) {
    int col = bn + tj * 16 + ln;
    float bv = biasf[col];
#pragma unroll
    for (int i = 0; i < 4; i++) {
      int row = bm + wv * 16 + qd * 4 + i;
      float v = acc[tj][i] + bv;
      if (fmode) ((float*)C)[(size_t)row * 512 + col] = v;
      else       ((unsigned short*)C)[(size_t)row * 512 + col] = f2bf(v);
    }
  }
}

// ---- attention core: 512 blocks x 32 m-rows, 39.9KB LDS (no v staging) ----
#define SST 132    // f32 per S row (pad); W bf16 overlays same rows (stride 264 u16)

__global__ __launch_bounds__(512) void k_attn(
    const unsigned short* __restrict__ XQ, const unsigned short* __restrict__ VT,
    const unsigned short* __restrict__ AT, const unsigned int* __restrict__ MB,
    const float* __restrict__ RBf, unsigned short* __restrict__ ATTO) {
  __shared__ __align__(16) float Sf[32 * SST];          // 16896 B
  __shared__ __align__(16) unsigned short qs[32][72];   // 4608
  __shared__ __align__(16) unsigned short ks[128][72];  // 18432
  unsigned short* Wb = (unsigned short*)Sf;

  // 512 blocks = (slot 0..63) x (xcd 0..7); m-quarter pinned to an XCD pair
  // -> per-L2 A_t hot set = 139 KB.
  const int i0 = blockIdx.x;
  const int xcd = i0 & 7, slot = i0 >> 3;
  const int mq = xcd >> 1;                 // 0..3 (32 m-rows each)
  const int bhid = slot * 2 + (xcd & 1);   // 0..127
  const int h = bhid & 7, b = bhid >> 3;
  const int bh = b * 8 + h;
  const int t = threadIdx.x;
  const int wv = t >> 6, l = t & 63, ln = l & 15, qd = l >> 4;

  // middle-section ids (also used for early A prefetch)
  const int ml = t >> 4, q16 = t & 15, n0 = q16 * 8;
  const int m = mq * 32 + ml;
  const unsigned short* abase = AT + (size_t)m * 128 + n0;
  // early prefetch: first TWO A planes + mask bits issued before staging
  // (cold latency hides under q/k staging + S-MFMA phases)
  uint4 ca = *(const uint4*)abase;
  uint4 cb = *(const uint4*)(abase + 16384);
  const unsigned int mb = MB[m];

  // ---- staging: q(32x64), k(128x64) ----
  for (int it = t; it < 1280; it += 512) {
    int row = it >> 3, ck = it & 7;
    if (row < 32) {
      const unsigned short* g = XQ + (size_t)(b * 128 + mq * 32 + row) * 1024 + h * 64 + ck * 8;
      *(uint4*)&qs[row][ck * 8] = *(const uint4*)g;
    } else {
      int nr = row - 32;
      const unsigned short* g = XQ + (size_t)(b * 128 + nr) * 1024 + 512 + h * 64 + ck * 8;
      *(uint4*)&ks[nr][ck * 8] = *(const uint4*)g;
    }
  }
  __syncthreads();

  // ---- S(32x128) = q @ k^T * scale : 8 waves ----
  {
    f32x4 accS[2] = {};
    const int rt = wv & 1, ch = wv >> 1;
#pragma unroll
    for (int kk = 0; kk < 64; kk += 32) {
      short8 af = *(const short8*)&qs[rt * 16 + ln][kk + qd * 8];
#pragma unroll
      for (int tj = 0; tj < 2; tj++) {
        short8 bf = *(const short8*)&ks[ch * 32 + tj * 16 + ln][kk + qd * 8];
        accS[tj] = __builtin_amdgcn_mfma_f32_16x16x32_bf16(af, bf, accS[tj], 0, 0, 0);
      }
    }
#pragma unroll
    for (int tj = 0; tj < 2; tj++)
#pragma unroll
      for (int i = 0; i < 4; i++)
        Sf[(rt * 16 + qd * 4 + i) * SST + ch * 32 + tj * 16 + ln] =
            accS[tj][i] * 0.125f;
  }
  __syncthreads();

  // ---- fused single-pass logits+softmax+W : 16 thr/row x 8 n-values ----
  // max-free softmax: logits O(10) << 88 (fp32 exp limit); dividing by the sum
  // afterwards is mathematically identical to ref softmax.
  {
    float sreg[8];
#pragma unroll
    for (int c4 = 0; c4 < 2; c4++) {
      float4 s4 = *(const float4*)&Sf[ml * SST + n0 + c4 * 4];
      sreg[c4 * 4 + 0] = s4.x; sreg[c4 * 4 + 1] = s4.y;
      sreg[c4 * 4 + 2] = s4.z; sreg[c4 * 4 + 3] = s4.w;
    }
    float wacc[8];
#pragma unroll
    for (int j = 0; j < 8; j++) wacc[j] = 0.0f;
    float sum = 0.0f;
#pragma unroll
    for (int r = 0; r < 17; r++) {
      uint4 nn;
      if (r + 2 < 17) nn = *(const uint4*)(abase + (r + 2) * 16384);
      float av[8];
      const unsigned short* a8 = (const unsigned short*)&ca;
#pragma unroll
      for (int j = 0; j < 8; j++) av[j] = bf2f(a8[j]);
      float s = 0.0f;
#pragma unroll
      for (int j = 0; j < 8; j++) s += sreg[j] * av[j];
      s += __shfl_xor(s, 1);
      s += __shfl_xor(s, 2);
      s += __shfl_xor(s, 4);
      s += __shfl_xor(s, 8);
      float e = ((mb >> r) & 1) ? 0.0f : __expf(s + RBf[h * 17 + r]);
      sum += e;
#pragma unroll
      for (int j = 0; j < 8; j++) wacc[j] += e * av[j];
      ca = cb; cb = nn;
    }
    const float inv = 1.0f / sum;
    unsigned short pk[8];
#pragma unroll
    for (int j = 0; j < 8; j++) pk[j] = f2bf(wacc[j] * inv);
    // W overlays same-row S bytes; the row's 16 threads are consecutive lanes
    // of one wave and all S reads precede these writes in program order
    *(uint4*)&Wb[ml * 264 + n0] = *(const uint4*)&pk[0];
  }
  __syncthreads();

  // ---- out(32x64) = W(32x128) @ v(128x64) : v^T fragments from L2 ----
  {
    f32x4 accO = {};
    const int rt = wv & 1, dt = wv >> 1;
    const int d = dt * 16 + ln;
    const unsigned short* vrow = VT + ((size_t)bh * 64 + d) * 128;
#pragma unroll
    for (int kk = 0; kk < 128; kk += 32) {
      short8 af = *(const short8*)&Wb[(rt * 16 + ln) * 264 + kk + qd * 8];
      short8 bf = *(const short8*)(vrow + kk + qd * 8);
      accO = __builtin_amdgcn_mfma_f32_16x16x32_bf16(af, bf, accO, 0, 0, 0);
    }
#pragma unroll
    for (int i = 0; i < 4; i++) {
      int row = b * 128 + mq * 32 + rt * 16 + qd * 4 + i;
      ATTO[(size_t)row * 512 + h * 64 + d] = f2bf(accO[i]);
    }
  }
}

extern "C" void kernel_launch(void* const* d_in, const int* in_sizes, int n_in,
                              void* d_out, int out_size, void* d_ws, size_t ws_size,
                              hipStream_t stream) {
  unsigned char* ws = (unsigned char*)d_ws;
  // 0:x 1:assignment 2:mask 3:q_w 4:kv_w 5:rel_bias 6:proj_w 7:proj_b
  k_phase1<<<896, 256, 0, stream>>>(d_in[0], d_in[3], d_in[4], d_in[1],
                                    (const unsigned char*)d_in[2],
                                    d_in[5], d_in[7], ws);
  k_attn<<<512, 512, 0, stream>>>((const unsigned short*)(ws + OFF_XQ),
                                  (const unsigned short*)(ws + OFF_VT),
                                  (const unsigned short*)(ws + OFF_AT),
                                  (const unsigned int*)(ws + OFF_MB),
                                  (const float*)(ws + OFF_RBF),
                                  (unsigned short*)(ws + OFF_ATTO));
  k_proj<<<dim3(32, 16), 256, 0, stream>>>((const unsigned short*)(ws + OFF_ATTO),
                                           d_in[6],
                                           (const float*)(ws + OFF_PBF),
                                           (const int*)ws, d_out);
}

// Round 15
// 112.416 us; speedup vs baseline: 1.2859x; 1.0045x over previous
//
#include <hip/hip_runtime.h>
#include <cstdint>
#include <cstddef>

#define DI __device__ __forceinline__

typedef __attribute__((ext_vector_type(8))) short short8;
typedef __attribute__((ext_vector_type(4))) float f32x4;

DI float bf2f(unsigned short u) {
  union { unsigned int i; float f; } c; c.i = ((unsigned int)u) << 16; return c.f;
}
DI unsigned short f2bf(float f) {
  union { float fl; unsigned int i; } c; c.fl = f;
  return (unsigned short)((c.i + 0x7FFFu + ((c.i >> 16) & 1u)) >> 16);
}

// ---- workspace layout (bytes) ----
static const size_t OFF_MB   = 256;                       // u32[128] mask bitwords
static const size_t OFF_RBF  = 1024;                      // f32[136] rel_bias
static const size_t OFF_PBF  = 2048;                      // f32[512] proj_b
static const size_t OFF_AT   = 16384;                     // bf16 A_t[17][128][128]
static const size_t OFF_XQ   = OFF_AT + 557056;           // bf16 [2048][1024] (q|k)
static const size_t OFF_VT   = OFF_XQ + (size_t)4194304;  // bf16 [128bh][64d][128n]
static const size_t OFF_ATTO = OFF_VT + (size_t)2097152;  // bf16 [2048][512]

// ---- phase1: blocks 0..127 prep (dispatch-first => starts early);
//              blocks 128..895 qkv GEMM (64x64 tile, ~3 blocks/CU) ----
__global__ __launch_bounds__(256) void k_phase1(
    const void* __restrict__ x, const void* __restrict__ qw,
    const void* __restrict__ kvw, const void* __restrict__ as,
    const unsigned char* __restrict__ mr, const void* __restrict__ rb,
    const void* __restrict__ pb, unsigned char* __restrict__ ws) {
  __shared__ unsigned short As[64 * 64];
  __shared__ unsigned short Bs[64 * 64];
  __shared__ int s_c0, s_3f, s_b1, s_odd;
  const int t = threadIdx.x;
  const int blk = blockIdx.x;

  if (t == 0) { s_c0 = 0; s_3f = 0; s_b1 = 0; s_odd = 0; }
  __syncthreads();
  // fmode self-detect (every block; 256B of x prefix, L2-broadcast after first)
  if (t < 128) {
    unsigned short u = ((const unsigned short*)x)[2 * t];
    int e = (u >> 7) & 0xFF;
    if (e >= 64 && e <= 150) atomicAdd(&s_c0, 1);
  }

  if (blk < 128) {
    // ============ prep: A_t repack via coalesced LDS transpose ============
    {
      int f3 = 0, b1 = 0, od = 0;
      for (int i = t; i < 2176; i += 256) {
        unsigned char bb = mr[i];
        if (bb == 0x3F) f3 = 1;
        if (bb) { if ((i & 3) == 1) b1 = 1; if (i & 3) od = 1; }
      }
      if (f3) atomicOr(&s_3f, 1);
      if (b1) atomicOr(&s_b1, 1);
      if (od) atomicOr(&s_odd, 1);
    }
    __syncthreads();
    const int fmode = (s_c0 >= 96) ? 0 : 1;
    const int mmode = s_3f ? (s_b1 ? 2 : 3) : (s_odd ? 0 : 1);
    unsigned short* At = (unsigned short*)(ws + OFF_AT);
    float* sL = (float*)As;                 // 1088 f32 = 4352 B staging
    // 128 mn-rows per block, 2 groups of 64: coalesced read -> LDS -> coalesced write
    for (int gi = 0; gi < 2; gi++) {
      int mn0 = blk * 128 + gi * 64;
      for (int j = t; j < 1088; j += 256)
        sL[j] = fmode ? ((const float*)as)[(size_t)mn0 * 17 + j]
                      : bf2f(((const unsigned short*)as)[(size_t)mn0 * 17 + j]);
      __syncthreads();
      for (int w = t; w < 1088; w += 256) {
        int r = w >> 6, jj = w & 63;
        At[(size_t)r * 16384 + mn0 + jj] = f2bf(sL[jj * 17 + r]);
      }
      __syncthreads();
    }
    if (blk == 0) {
      if (t == 0) { ((int*)ws)[0] = fmode; ((int*)ws)[1] = mmode; }
      unsigned int* MB = (unsigned int*)(ws + OFF_MB);
      float* RBf = (float*)(ws + OFF_RBF);
      float* PBf = (float*)(ws + OFF_PBF);
      if (t < 128) {
        unsigned int bits = 0;
        for (int r = 0; r < 17; r++) {
          int j = t * 17 + r, v;
          if (mmode == 0)      v = mr[j] != 0;
          else if (mmode == 1) v = ((const int*)mr)[j] != 0;
          else if (mmode == 2) v = ((const unsigned short*)mr)[j] != 0;
          else                 v = ((const float*)mr)[j] != 0.0f;
          bits |= (unsigned int)v << r;
        }
        MB[t] = bits;
      }
      for (int j = t; j < 136; j += 256)
        RBf[j] = fmode ? ((const float*)rb)[j] : bf2f(((const unsigned short*)rb)[j]);
      for (int j = t; j < 512; j += 256)
        PBf[j] = fmode ? ((const float*)pb)[j] : bf2f(((const unsigned short*)pb)[j]);
    }
  } else {
    // ============ qkv GEMM: C[2048,1536] = x @ [qw;kvw]^T, 64x64 tile ============
    __syncthreads();
    const int fmode = (s_c0 >= 96) ? 0 : 1;
    const int gb2 = blk - 128;
    const int bm = (gb2 & 31) * 64, bn = (gb2 >> 5) * 64;
    const int wv = t >> 6, l = t & 63, ln = l & 15, qd = l >> 4;
    f32x4 acc[4] = {};
    const int g_row8 = l >> 3;
    const int g_ck = (l & 7) ^ g_row8;
    const int s_row = t >> 2;
    const int s_cb = (t & 3) * 2;
    for (int k0 = 0; k0 < 512; k0 += 64) {
      if (!fmode) {
        const unsigned short* xb = (const unsigned short*)x;
#pragma unroll
        for (int jj = 0; jj < 2; jj++) {
          int j = 2 * wv + jj;
          const unsigned short* g = xb + (size_t)(bm + j * 8 + g_row8) * 512 + k0 + g_ck * 8;
          __builtin_amdgcn_global_load_lds(
              (const __attribute__((address_space(1))) unsigned int*)g,
              (__attribute__((address_space(3))) unsigned int*)(&As[j * 512 + l * 8]),
              16, 0, 0);
        }
#pragma unroll
        for (int jj = 0; jj < 2; jj++) {
          int j = 2 * wv + jj;
          int row = bn + j * 8 + g_row8;
          const unsigned short* base = (row < 512)
              ? (const unsigned short*)qw + (size_t)row * 512
              : (const unsigned short*)kvw + (size_t)(row - 512) * 512;
          const unsigned short* g = base + k0 + g_ck * 8;
          __builtin_amdgcn_global_load_lds(
              (const __attribute__((address_space(1))) unsigned int*)g,
              (__attribute__((address_space(3))) unsigned int*)(&Bs[j * 512 + l * 8]),
              16, 0, 0);
        }
      } else {
        const float* ga = (const float*)x + (size_t)(bm + s_row) * 512 + k0 + s_cb * 8;
        int brow = bn + s_row;
        const float* gb = ((brow < 512) ? (const float*)qw + (size_t)brow * 512
                                        : (const float*)kvw + (size_t)(brow - 512) * 512)
                          + k0 + s_cb * 8;
#pragma unroll
        for (int cc = 0; cc < 2; cc++) {
          unsigned short ta[8], tb[8];
#pragma unroll
          for (int u = 0; u < 8; u++) { ta[u] = f2bf(ga[cc * 8 + u]); tb[u] = f2bf(gb[cc * 8 + u]); }
          int pc = (s_cb + cc) ^ (s_row & 7);
          *(uint4*)&As[s_row * 64 + pc * 8] = *(const uint4*)ta;
          *(uint4*)&Bs[s_row * 64 + pc * 8] = *(const uint4*)tb;
        }
      }
      __syncthreads();
#pragma unroll
      for (int kk = 0; kk < 64; kk += 32) {
        int c = (kk >> 3) + qd;
        short8 af = *(const short8*)&As[(wv * 16 + ln) * 64 + ((c ^ (ln & 7)) * 8)];
#pragma unroll
        for (int tj = 0; tj < 4; tj++) {
          short8 bf = *(const short8*)&Bs[(tj * 16 + ln) * 64 + ((c ^ (ln & 7)) * 8)];
          acc[tj] = __builtin_amdgcn_mfma_f32_16x16x32_bf16(af, bf, acc[tj], 0, 0, 0);
        }
      }
      __syncthreads();
    }
    unsigned short* XQ = (unsigned short*)(ws + OFF_XQ);
    unsigned short* VT = (unsigned short*)(ws + OFF_VT);
#pragma unroll
    for (int tj = 0; tj < 4; tj++) {
      int col = bn + tj * 16 + ln;
      if (col >= 1024) {                       // V -> transposed, packed 8B store
        int c1 = col - 1024;
        int row0 = bm + wv * 16 + qd * 4;
        int bh = (row0 >> 7) * 8 + (c1 >> 6);
        ushort4 pk;
        pk.x = f2bf(acc[tj][0]); pk.y = f2bf(acc[tj][1]);
        pk.z = f2bf(acc[tj][2]); pk.w = f2bf(acc[tj][3]);
        *(ushort4*)&VT[((size_t)bh * 64 + (c1 & 63)) * 128 + (row0 & 127)] = pk;
      } else {
#pragma unroll
        for (int i = 0; i < 4; i++) {
          int row = bm + wv * 16 + qd * 4 + i;
          XQ[(size_t)row * 1024 + col] = f2bf(acc[tj][i]);
        }
      }
    }
  }
}

// ---- proj GEMM: 64x32 tiles, 512 blocks (~2-3/CU) ----
__global__ __launch_bounds__(256) void k_proj(
    const unsigned short* __restrict__ A,   // ATTO bf16 [2048][512]
    const void* __restrict__ Bw,            // proj_w raw
    const float* __restrict__ biasf,
    const int* __restrict__ flags, void* __restrict__ C) {
  __shared__ unsigned short As[64 * 64];
  __shared__ unsigned short Bs[32 * 64];
  const int fmode = flags[0];
  const int bm = blockIdx.x * 64, bn = blockIdx.y * 32;
  const int t = threadIdx.x, wv = t >> 6, l = t & 63, ln = l & 15, qd = l >> 4;
  f32x4 acc[2] = {};
  const int g_row8 = l >> 3;
  const int g_ck = (l & 7) ^ g_row8;
  for (int k0 = 0; k0 < 512; k0 += 64) {
#pragma unroll
    for (int jj = 0; jj < 2; jj++) {
      int j = 2 * wv + jj;
      const unsigned short* g = A + (size_t)(bm + j * 8 + g_row8) * 512 + k0 + g_ck * 8;
      __builtin_amdgcn_global_load_lds(
          (const __attribute__((address_space(1))) unsigned int*)g,
          (__attribute__((address_space(3))) unsigned int*)(&As[j * 512 + l * 8]),
          16, 0, 0);
    }
    if (!fmode) {
      int row = bn + wv * 8 + g_row8;
      const unsigned short* g = (const unsigned short*)Bw + (size_t)row * 512 + k0 + g_ck * 8;
      __builtin_amdgcn_global_load_lds(
          (const __attribute__((address_space(1))) unsigned int*)g,
          (__attribute__((address_space(3))) unsigned int*)(&Bs[wv * 512 + l * 8]),
          16, 0, 0);
    } else {
      int row = t >> 3, cb = t & 7;     // 32 rows x 8 chunks
      const float* g = (const float*)Bw + (size_t)(bn + row) * 512 + k0 + cb * 8;
      unsigned short tb[8];
#pragma unroll
      for (int u = 0; u < 8; u++) tb[u] = f2bf(g[u]);
      int pc = cb ^ (row & 7);
      *(uint4*)&Bs[row * 64 + pc * 8] = *(const uint4*)tb;
    }
    __syncthreads();
#pragma unroll
    for (int kk = 0; kk < 64; kk += 32) {
      int c = (kk >> 3) + qd;
      short8 af = *(const short8*)&As[(wv * 16 + ln) * 64 + ((c ^ (ln & 7)) * 8)];
#pragma unroll
      for (int tj = 0; tj < 2; tj++) {
        short8 bf = *(const short8*)&Bs[(tj * 16 + ln) * 64 + ((c ^ (ln & 7)) * 8)];
        acc[tj] = __builtin_amdgcn_mfma_f32_16x16x32_bf16(af, bf, acc[tj], 0, 0, 0);
      }
    }
    __syncthreads();
  }
#pragma unroll
  for (int tj = 0; tj < 2; tj++) {
    int col = bn + tj * 16 + ln;
    float bv = biasf[col];
#pragma unroll
    for (int i = 0; i < 4; i++) {
      int row = bm + wv * 16 + qd * 4 + i;
      float v = acc[tj][i] + bv;
      if (fmode) ((float*)C)[(size_t)row * 512 + col] = v;
      else       ((unsigned short*)C)[(size_t)row * 512 + col] = f2bf(v);
    }
  }
}

// ---- attention core: 1024 blocks x 16 m-rows, 29.2KB LDS -> 4 blocks/CU ----
#define SST 132    // f32 per S row (pad); W bf16 overlays same rows (stride 264 u16)

__global__ __launch_bounds__(512) void k_attn(
    const unsigned short* __restrict__ XQ, const unsigned short* __restrict__ VT,
    const unsigned short* __restrict__ AT, const unsigned int* __restrict__ MB,
    const float* __restrict__ RBf, unsigned short* __restrict__ ATTO) {
  __shared__ __align__(16) float Sf[16 * SST];          // 8448 B
  __shared__ __align__(16) unsigned short qs[16][72];   // 2304
  __shared__ __align__(16) unsigned short ks[128][72];  // 18432
  unsigned short* Wb = (unsigned short*)Sf;

  // 1024 blocks = (slot 0..127) x (xcd 0..7); m-eighth pinned to one XCD
  // -> per-L2 A_t hot set = 17*16*128*2 = 69 KB.
  const int i0 = blockIdx.x;
  const int xcd = i0 & 7, slot = i0 >> 3;
  const int mq = xcd;                      // 0..7 (16 m-rows each)
  const int bhid = slot;                   // 0..127
  const int h = bhid & 7, b = bhid >> 3;
  const int bh = b * 8 + h;
  const int t = threadIdx.x;
  const int wv = t >> 6, l = t & 63, ln = l & 15, qd = l >> 4;

  // middle-section ids (also used for early A prefetch): 32 thr/row x 4 n-vals
  const int ml = t >> 5, q32 = t & 31, n0 = q32 * 4;
  const int m = mq * 16 + ml;
  const unsigned short* abase = AT + (size_t)m * 128 + n0;
  // early prefetch: first TWO A planes + mask bits issued before staging
  uint2 ca = *(const uint2*)abase;
  uint2 cb = *(const uint2*)(abase + 16384);
  const unsigned int mb = MB[m];

  // ---- staging: q(16x64)=128 uint4, k(128x64)=1024 uint4 ----
  for (int it = t; it < 1152; it += 512) {
    int row = it >> 3, ck = it & 7;
    if (row < 16) {
      const unsigned short* g = XQ + (size_t)(b * 128 + mq * 16 + row) * 1024 + h * 64 + ck * 8;
      *(uint4*)&qs[row][ck * 8] = *(const uint4*)g;
    } else {
      int nr = row - 16;
      const unsigned short* g = XQ + (size_t)(b * 128 + nr) * 1024 + 512 + h * 64 + ck * 8;
      *(uint4*)&ks[nr][ck * 8] = *(const uint4*)g;
    }
  }
  __syncthreads();

  // ---- S(16x128) = q @ k^T * scale : 8 waves, one 16x16 tile each ----
  {
    f32x4 accS = {};
#pragma unroll
    for (int kk = 0; kk < 64; kk += 32) {
      short8 af = *(const short8*)&qs[ln][kk + qd * 8];
      short8 bf = *(const short8*)&ks[wv * 16 + ln][kk + qd * 8];
      accS = __builtin_amdgcn_mfma_f32_16x16x32_bf16(af, bf, accS, 0, 0, 0);
    }
#pragma unroll
    for (int i = 0; i < 4; i++)
      Sf[(qd * 4 + i) * SST + wv * 16 + ln] = accS[i] * 0.125f;
  }
  __syncthreads();

  // ---- fused single-pass logits+softmax+W : 32 thr/row x 4 n-values ----
  // max-free softmax: logits O(10) << 88 (fp32 exp limit); dividing by the sum
  // afterwards is mathematically identical to ref softmax.
  {
    float sreg[4];
    {
      float4 s4 = *(const float4*)&Sf[ml * SST + n0];
      sreg[0] = s4.x; sreg[1] = s4.y; sreg[2] = s4.z; sreg[3] = s4.w;
    }
    float wacc[4];
#pragma unroll
    for (int j = 0; j < 4; j++) wacc[j] = 0.0f;
    float sum = 0.0f;
#pragma unroll
    for (int r = 0; r < 17; r++) {
      uint2 nn;
      if (r + 2 < 17) nn = *(const uint2*)(abase + (r + 2) * 16384);
      float av[4];
      const unsigned short* a8 = (const unsigned short*)&ca;
#pragma unroll
      for (int j = 0; j < 4; j++) av[j] = bf2f(a8[j]);
      float s = sreg[0] * av[0] + sreg[1] * av[1] + sreg[2] * av[2] + sreg[3] * av[3];
      s += __shfl_xor(s, 1);
      s += __shfl_xor(s, 2);
      s += __shfl_xor(s, 4);
      s += __shfl_xor(s, 8);
      s += __shfl_xor(s, 16);
      float e = ((mb >> r) & 1) ? 0.0f : __expf(s + RBf[h * 17 + r]);
      sum += e;
#pragma unroll
      for (int j = 0; j < 4; j++) wacc[j] += e * av[j];
      ca = cb; cb = nn;
    }
    const float inv = 1.0f / sum;
    unsigned short pk[4];
#pragma unroll
    for (int j = 0; j < 4; j++) pk[j] = f2bf(wacc[j] * inv);
    // W overlays same-row S bytes; the row's 32 threads live in one wave
    // (lanes 0-31 or 32-63) and all S reads precede these writes in program order
    *(uint2*)&Wb[ml * 264 + n0] = *(const uint2*)&pk[0];
  }
  __syncthreads();

  // ---- out(16x64) = W(16x128) @ v(128x64) : waves 0-3, one d-tile each ----
  if (wv < 4) {
    f32x4 accO = {};
    const int d = wv * 16 + ln;
    const unsigned short* vrow = VT + ((size_t)bh * 64 + d) * 128;
#pragma unroll
    for (int kk = 0; kk < 128; kk += 32) {
      short8 af = *(const short8*)&Wb[ln * 264 + kk + qd * 8];
      short8 bf = *(const short8*)(vrow + kk + qd * 8);
      accO = __builtin_amdgcn_mfma_f32_16x16x32_bf16(af, bf, accO, 0, 0, 0);
    }
#pragma unroll
    for (int i = 0; i < 4; i++) {
      int row = b * 128 + mq * 16 + qd * 4 + i;
      ATTO[(size_t)row * 512 + h * 64 + d] = f2bf(accO[i]);
    }
  }
}

extern "C" void kernel_launch(void* const* d_in, const int* in_sizes, int n_in,
                              void* d_out, int out_size, void* d_ws, size_t ws_size,
                              hipStream_t stream) {
  unsigned char* ws = (unsigned char*)d_ws;
  // 0:x 1:assignment 2:mask 3:q_w 4:kv_w 5:rel_bias 6:proj_w 7:proj_b
  k_phase1<<<896, 256, 0, stream>>>(d_in[0], d_in[3], d_in[4], d_in[1],
                                    (const unsigned char*)d_in[2],
                                    d_in[5], d_in[7], ws);
  k_attn<<<1024, 512, 0, stream>>>((const unsigned short*)(ws + OFF_XQ),
                                   (const unsigned short*)(ws + OFF_VT),
                                   (const unsigned short*)(ws + OFF_AT),
                                   (const unsigned int*)(ws + OFF_MB),
                                   (const float*)(ws + OFF_RBF),
                                   (unsigned short*)(ws + OFF_ATTO));
  k_proj<<<dim3(32, 16), 256, 0, stream>>>((const unsigned short*)(ws + OFF_ATTO),
                                           d_in[6],
                                           (const float*)(ws + OFF_PBF),
                                           (const int*)ws, d_out);
}